// Round 11
// baseline (9684.929 us; speedup 1.0000x reference)
//
#include <hip/hip_runtime.h>
#include <math.h>

#define NEIG 256
#define LDQ 256
#define SMLSIZ 25
#define EPSD 1.1102230246251565e-16
#define SAFMND 2.2250738585072014e-308

// ======================= scalar LAPACK helpers =======================
__device__ __forceinline__ double fsign(double a, double b){ return copysign(a, b); }

__device__ __forceinline__ double dlapy2(double x, double y){
  double xa = fabs(x), ya = fabs(y);
  double w = fmax(xa, ya), z = fmin(xa, ya);
  if (z == 0.0) return w;
  double t = z / w;
  return w * sqrt(1.0 + t*t);
}

// LAPACK >= 3.10 dlartg (numpy's OpenBLAS): c >= 0 always.
__device__ void dlartg(double f, double g, double& c, double& s, double& r){
  const double safmin = SAFMND;
  const double safmax = 1.0/SAFMND;
  double f1 = fabs(f), g1 = fabs(g);
  if (g == 0.0){ c = 1.0; s = 0.0; r = f; }
  else if (f == 0.0){ c = 0.0; s = copysign(1.0, g); r = g1; }
  else {
    double rtmin = sqrt(safmin);
    double rtmax = sqrt(safmax/2.0);
    if (f1 > rtmin && f1 < rtmax && g1 > rtmin && g1 < rtmax){
      double d = sqrt(f*f + g*g);
      c = f1/d;
      r = copysign(d, f);
      s = g/r;
    } else {
      double u = fmin(safmax, fmax(safmin, fmax(f1, g1)));
      double fs = f/u, gs = g/u;
      double d = sqrt(fs*fs + gs*gs);
      c = fabs(fs)/d;
      r = copysign(d, f);
      s = gs/r;
      r = r*u;
    }
  }
}

__device__ void dlaev2(double a, double b, double c, double& rt1, double& rt2, double& cs1, double& sn1){
  double sm = a + c, df = a - c, adf = fabs(df), tb = b + b, ab = fabs(tb);
  double acmx, acmn;
  if (fabs(a) > fabs(c)){ acmx = a; acmn = c; } else { acmx = c; acmn = a; }
  double rt;
  if (adf > ab) rt = adf*sqrt(1.0 + (ab/adf)*(ab/adf));
  else if (adf < ab) rt = ab*sqrt(1.0 + (adf/ab)*(adf/ab));
  else rt = ab*sqrt(2.0);
  int sgn1;
  if (sm < 0.0){ rt1 = 0.5*(sm - rt); sgn1 = -1; rt2 = (acmx/rt1)*acmn - (b/rt1)*b; }
  else if (sm > 0.0){ rt1 = 0.5*(sm + rt); sgn1 = 1; rt2 = (acmx/rt1)*acmn - (b/rt1)*b; }
  else { rt1 = 0.5*rt; rt2 = -0.5*rt; sgn1 = 1; }
  double cs; int sgn2;
  if (df >= 0.0){ cs = df + rt; sgn2 = 1; } else { cs = df - rt; sgn2 = -1; }
  double acs = fabs(cs);
  if (acs > ab){ double ct = -tb/cs; sn1 = 1.0/sqrt(1.0 + ct*ct); cs1 = ct*sn1; }
  else {
    if (ab == 0.0){ cs1 = 1.0; sn1 = 0.0; }
    else { double tn = -cs/tb; cs1 = 1.0/sqrt(1.0 + tn*tn); sn1 = tn*cs1; }
  }
  if (sgn1 == sgn2){ double tn = cs1; cs1 = -sn1; sn1 = tn; }
}

__device__ void dlamrg(int n1, int n2, const double* a, int dtrd1, int dtrd2, int* index){
  int n1sv = n1, n2sv = n2, ind1, ind2;
  if (dtrd1 > 0) ind1 = 1; else ind1 = n1;
  if (dtrd2 > 0) ind2 = 1 + n1; else ind2 = n1 + n2;
  int i = 1;
  while (n1sv > 0 && n2sv > 0){
    if (a[ind1] <= a[ind2]){ index[i++] = ind1; ind1 += dtrd1; n1sv--; }
    else { index[i++] = ind2; ind2 += dtrd2; n2sv--; }
  }
  if (n1sv == 0){ while (n2sv > 0){ index[i++] = ind2; ind2 += dtrd2; n2sv--; } }
  else { while (n1sv > 0){ index[i++] = ind1; ind1 += dtrd1; n1sv--; } }
}

// ======================= dsteqr (serial, compz='I') =======================
__device__ void dsteqr_serial(int n, double* d, double* e, double* zb, int ldz, double* work){
#define ZZL(i,j) zb[((i)-1) + (size_t)((j)-1)*ldz]
  const double eps = EPSD, eps2 = EPSD*EPSD, safmin = SAFMND;
  const double ssfmax = sqrt(1.0/SAFMND)/3.0;
  const double ssfmin = sqrt(SAFMND)/(EPSD*EPSD);
  if (n <= 0) return;
  if (n == 1){ ZZL(1,1) = 1.0; return; }
  for (int j = 1; j <= n; j++)
    for (int i = 1; i <= n; i++)
      ZZL(i,j) = (i == j) ? 1.0 : 0.0;
  int nmaxit = n*30, jtot = 0;
  int l1 = 1, nm1 = n - 1;
  while (true){
    if (l1 > n) break;
    if (l1 > 1) e[l1-1] = 0.0;
    int m = n;
    if (l1 <= nm1){
      for (int mm = l1; mm <= nm1; mm++){
        double tst = fabs(e[mm]);
        if (tst == 0.0){ m = mm; break; }
        if (tst <= (sqrt(fabs(d[mm]))*sqrt(fabs(d[mm+1])))*eps){ e[mm] = 0.0; m = mm; break; }
      }
    }
    int l = l1, lsv = l, lend = m, lendsv = lend;
    l1 = m + 1;
    if (lend == l) continue;
    double anorm = 0.0;
    for (int i = l; i <= lend; i++) anorm = fmax(anorm, fabs(d[i]));
    for (int i = l; i <= lend-1; i++) anorm = fmax(anorm, fabs(e[i]));
    int iscale = 0;
    if (anorm == 0.0) continue;
    if (anorm > ssfmax){
      iscale = 1; double f = ssfmax/anorm;
      for (int i = l; i <= lend; i++) d[i] *= f;
      for (int i = l; i <= lend-1; i++) e[i] *= f;
    } else if (anorm < ssfmin){
      iscale = 2; double f = ssfmin/anorm;
      for (int i = l; i <= lend; i++) d[i] *= f;
      for (int i = l; i <= lend-1; i++) e[i] *= f;
    }
    if (fabs(d[lend]) < fabs(d[l])){ lend = lsv; l = lendsv; }
    if (lend > l){
      while (true){
        int mm = lend;
        if (l != lend){
          for (int m2 = l; m2 <= lend-1; m2++){
            double tst = e[m2]*e[m2];
            if (tst <= (eps2*fabs(d[m2]))*fabs(d[m2+1]) + safmin){ mm = m2; break; }
          }
        }
        if (mm < lend) e[mm] = 0.0;
        double p = d[l];
        if (mm == l){
          d[l] = p; l++;
          if (l <= lend) continue;
          break;
        }
        if (mm == l+1){
          double rt1, rt2, c, s;
          dlaev2(d[l], e[l], d[l+1], rt1, rt2, c, s);
          work[l] = c; work[n-1+l] = s;
          for (int i = 1; i <= n; i++){
            double t2 = ZZL(i, l+1);
            ZZL(i, l+1) = c*t2 - s*ZZL(i, l);
            ZZL(i, l)   = s*t2 + c*ZZL(i, l);
          }
          d[l] = rt1; d[l+1] = rt2; e[l] = 0.0;
          l += 2;
          if (l <= lend) continue;
          break;
        }
        if (jtot == nmaxit) break;
        jtot++;
        double g = (d[l+1]-p)/(2.0*e[l]);
        double r = dlapy2(g, 1.0);
        g = d[mm] - p + (e[l]/(g + fsign(r, g)));
        double s = 1.0, c = 1.0;
        p = 0.0;
        for (int i = mm-1; i >= l; i--){
          double f = s*e[i], b = c*e[i];
          dlartg(g, f, c, s, r);
          if (i != mm-1) e[i+1] = r;
          g = d[i+1] - p;
          r = (d[i]-g)*s + 2.0*c*b;
          p = s*r;
          d[i+1] = g + p;
          g = c*r - b;
          work[i] = c; work[n-1+i] = -s;
        }
        {
          int cnt = mm - l + 1;
          for (int jj = cnt-1; jj >= 1; jj--){
            double ct = work[l+jj-1], st = work[n-1+l+jj-1];
            for (int i = 1; i <= n; i++){
              double t2 = ZZL(i, l+jj);
              ZZL(i, l+jj)   = ct*t2 - st*ZZL(i, l+jj-1);
              ZZL(i, l+jj-1) = st*t2 + ct*ZZL(i, l+jj-1);
            }
          }
        }
        d[l] -= p;
        e[l] = g;
      }
    } else {
      while (true){
        int mm = lend;
        if (l != lend){
          for (int m2 = l; m2 >= lend+1; m2--){
            double tst = e[m2-1]*e[m2-1];
            if (tst <= (eps2*fabs(d[m2]))*fabs(d[m2-1]) + safmin){ mm = m2; break; }
          }
        }
        if (mm > lend) e[mm-1] = 0.0;
        double p = d[l];
        if (mm == l){
          d[l] = p; l--;
          if (l >= lend) continue;
          break;
        }
        if (mm == l-1){
          double rt1, rt2, c, s;
          dlaev2(d[l-1], e[l-1], d[l], rt1, rt2, c, s);
          work[mm] = c; work[n-1+mm] = s;
          for (int i = 1; i <= n; i++){
            double t2 = ZZL(i, l);
            ZZL(i, l)   = c*t2 - s*ZZL(i, l-1);
            ZZL(i, l-1) = s*t2 + c*ZZL(i, l-1);
          }
          d[l-1] = rt1; d[l] = rt2; e[l-1] = 0.0;
          l -= 2;
          if (l >= lend) continue;
          break;
        }
        if (jtot == nmaxit) break;
        jtot++;
        double g = (d[l-1]-p)/(2.0*e[l-1]);
        double r = dlapy2(g, 1.0);
        g = d[mm] - p + (e[l-1]/(g + fsign(r, g)));
        double s = 1.0, c = 1.0;
        p = 0.0;
        for (int i = mm; i <= l-1; i++){
          double f = s*e[i], b = c*e[i];
          dlartg(g, f, c, s, r);
          if (i != mm) e[i-1] = r;
          g = d[i] - p;
          r = (d[i+1]-g)*s + 2.0*c*b;
          p = s*r;
          d[i] = g + p;
          g = c*r - b;
          work[i] = c; work[n-1+i] = s;
        }
        {
          int cnt = l - mm + 1;
          for (int jj = 1; jj <= cnt-1; jj++){
            double ct = work[mm+jj-1], st = work[n-1+mm+jj-1];
            for (int i = 1; i <= n; i++){
              double t2 = ZZL(i, mm+jj);
              ZZL(i, mm+jj)   = ct*t2 - st*ZZL(i, mm+jj-1);
              ZZL(i, mm+jj-1) = st*t2 + ct*ZZL(i, mm+jj-1);
            }
          }
        }
        d[l] -= p;
        e[l-1] = g;
      }
    }
    if (iscale == 1){
      double f = anorm/ssfmax;
      for (int i = lsv; i <= lendsv; i++) d[i] *= f;
      for (int i = lsv; i <= lendsv-1; i++) e[i] *= f;
    } else if (iscale == 2){
      double f = anorm/ssfmin;
      for (int i = lsv; i <= lendsv; i++) d[i] *= f;
      for (int i = lsv; i <= lendsv-1; i++) e[i] *= f;
    }
  }
  for (int ii = 2; ii <= n; ii++){
    int i = ii - 1, kk = i;
    double p = d[i];
    for (int j = ii; j <= n; j++){ if (d[j] < p){ kk = j; p = d[j]; } }
    if (kk != i){
      d[kk] = d[i]; d[i] = p;
      for (int r = 1; r <= n; r++){ double t2 = ZZL(r,i); ZZL(r,i) = ZZL(r,kk); ZZL(r,kk) = t2; }
    }
  }
#undef ZZL
}

// ======================= dlaed5 (strided delta) =======================
__device__ void dlaed5(int i, const double* d, const double* z, double* delta, int dst,
                       double rho, double& dlam){
#define DL5(j) delta[(size_t)((j)-1)*dst]
  double del = d[2] - d[1];
  if (i == 1){
    double w = 1.0 + 2.0*rho*(z[2]*z[2] - z[1]*z[1])/del;
    if (w > 0.0){
      double b = del + rho*(z[1]*z[1] + z[2]*z[2]);
      double c = rho*z[1]*z[1]*del;
      double tau = 2.0*c/(b + sqrt(fabs(b*b - 4.0*c)));
      dlam = d[1] + tau;
      DL5(1) = -z[1]/tau;
      DL5(2) = z[2]/(del - tau);
    } else {
      double b = -del + rho*(z[1]*z[1] + z[2]*z[2]);
      double c = rho*z[2]*z[2]*del;
      double tau;
      if (b > 0.0) tau = -2.0*c/(b + sqrt(b*b + 4.0*c));
      else tau = (b - sqrt(b*b + 4.0*c))/2.0;
      dlam = d[2] + tau;
      DL5(1) = -z[1]/(del + tau);
      DL5(2) = -z[2]/tau;
    }
    double temp = sqrt(DL5(1)*DL5(1) + DL5(2)*DL5(2));
    DL5(1) /= temp; DL5(2) /= temp;
  } else {
    double b = -del + rho*(z[1]*z[1] + z[2]*z[2]);
    double c = rho*z[2]*z[2]*del;
    double tau;
    if (b > 0.0) tau = (b + sqrt(b*b + 4.0*c))/2.0;
    else tau = 2.0*c/(-b + sqrt(b*b + 4.0*c));
    dlam = d[2] + tau;
    DL5(1) = -z[1]/(del + tau);
    DL5(2) = -z[2]/tau;
    double temp = sqrt(DL5(1)*DL5(1) + DL5(2)*DL5(2));
    DL5(1) /= temp; DL5(2) /= temp;
  }
#undef DL5
}

// ======================= dlaed6 =======================
__device__ void dlaed6(int kniter, bool orgati, double rho, const double* dd, const double* zz,
                       double finit, double& tau, int& info){
  const int maxit = 40;
  info = 0;
  double lbd, ubd;
  if (orgati){ lbd = dd[2]; ubd = dd[3]; }
  else { lbd = dd[1]; ubd = dd[2]; }
  if (finit < 0.0) lbd = 0.0; else ubd = 0.0;
  tau = 0.0;
  if (kniter == 2){
    double temp, a, b, c;
    if (orgati){
      temp = (dd[3] + dd[2])/2.0;
      c = rho + zz[1]/(dd[1] - temp);
      a = c*(dd[2] + dd[3]) + zz[2] + zz[3];
      b = c*dd[2]*dd[3] + zz[2]*dd[3] + zz[3]*dd[2];
    } else {
      temp = (dd[1] + dd[2])/2.0;
      c = rho + zz[3]/(dd[3] - temp);
      a = c*(dd[1] + dd[2]) + zz[1] + zz[2];
      b = c*dd[1]*dd[2] + zz[1]*dd[2] + zz[2]*dd[1];
    }
    temp = fmax(fabs(a), fmax(fabs(b), fabs(c)));
    a /= temp; b /= temp; c /= temp;
    if (c == 0.0) tau = b/a;
    else if (a <= 0.0) tau = (a - sqrt(fabs(a*a - 4.0*b*c)))/(2.0*c);
    else tau = 2.0*b/(a + sqrt(fabs(a*a - 4.0*b*c)));
    if (tau < lbd || tau > ubd) tau = (lbd + ubd)/2.0;
    if (dd[1] == tau || dd[2] == tau || dd[3] == tau){
      tau = 0.0;
    } else {
      temp = finit + tau*zz[1]/(dd[1]*(dd[1]-tau))
                   + tau*zz[2]/(dd[2]*(dd[2]-tau))
                   + tau*zz[3]/(dd[3]*(dd[3]-tau));
      if (temp <= 0.0) lbd = tau; else ubd = tau;
      if (fabs(finit) <= fabs(temp)) tau = 0.0;
    }
  }
  const double small1 = 0x1p-340, sminv1 = 0x1p+340;
  const double small2 = small1*small1, sminv2 = sminv1*sminv1;
  double dscale[4], zscale[4];
  double temp2;
  if (orgati) temp2 = fmin(fabs(dd[2]-tau), fabs(dd[3]-tau));
  else temp2 = fmin(fabs(dd[1]-tau), fabs(dd[2]-tau));
  bool scalef = false;
  double sclinv = 1.0;
  if (temp2 <= small1){
    scalef = true;
    double sclfac;
    if (temp2 <= small2){ sclfac = sminv2; sclinv = small2; }
    else { sclfac = sminv1; sclinv = small1; }
    for (int i = 1; i <= 3; i++){ dscale[i] = dd[i]*sclfac; zscale[i] = zz[i]*sclfac; }
    tau *= sclfac; lbd *= sclfac; ubd *= sclfac;
  } else {
    for (int i = 1; i <= 3; i++){ dscale[i] = dd[i]; zscale[i] = zz[i]; }
  }
  double fc = 0.0, df = 0.0, ddf = 0.0;
  for (int i = 1; i <= 3; i++){
    double t = 1.0/(dscale[i] - tau);
    double t1 = zscale[i]*t;
    double t2 = t1*t;
    double t3 = t2*t;
    fc += t1/dscale[i];
    df += t2;
    ddf += t3;
  }
  double f = finit + tau*fc;
  if (fabs(f) > 0.0){
    if (f <= 0.0) lbd = tau; else ubd = tau;
    bool converged = false;
    for (int it = 2; it <= maxit; it++){
      double temp1v, temp2v;
      if (orgati){ temp1v = dscale[2] - tau; temp2v = dscale[3] - tau; }
      else { temp1v = dscale[1] - tau; temp2v = dscale[2] - tau; }
      double a = (temp1v + temp2v)*f - temp1v*temp2v*df;
      double b = temp1v*temp2v*f;
      double c = f - (temp1v + temp2v)*df + temp1v*temp2v*ddf;
      double temp = fmax(fabs(a), fmax(fabs(b), fabs(c)));
      a /= temp; b /= temp; c /= temp;
      double eta;
      if (c == 0.0) eta = b/a;
      else if (a <= 0.0) eta = (a - sqrt(fabs(a*a - 4.0*b*c)))/(2.0*c);
      else eta = 2.0*b/(a + sqrt(fabs(a*a - 4.0*b*c)));
      if (f*eta >= 0.0) eta = -f/df;
      tau += eta;
      if (tau < lbd || tau > ubd) tau = (lbd + ubd)/2.0;
      fc = 0.0; df = 0.0; ddf = 0.0;
      double erretm = 0.0;
      bool hitzero = false;
      for (int i = 1; i <= 3; i++){
        if ((dscale[i] - tau) != 0.0){
          double t = 1.0/(dscale[i] - tau);
          double t1 = zscale[i]*t;
          double t2 = t1*t;
          double t3 = t2*t;
          double t4 = t1/dscale[i];
          fc += t4;
          erretm += fabs(t4);
          df += t2;
          ddf += t3;
        } else { hitzero = true; break; }
      }
      if (hitzero){ converged = true; break; }
      f = finit + tau*fc;
      erretm = 8.0*(fabs(finit) + fabs(tau)*erretm) + fabs(tau)*df;
      if (fabs(f) <= EPSD*erretm){ converged = true; break; }
      if (f <= 0.0) lbd = tau; else ubd = tau;
    }
    if (!converged) info = 1;
  }
  if (scalef) tau *= sclinv;
}

// ======================= dlaed4 (strided delta) =======================
__device__ void dlaed4(int n, int i, const double* d, const double* z, double* delta, int dst,
                       double rho, double& dlam, int& info){
#define DL(j) delta[(size_t)((j)-1)*dst]
  const int maxit = 30;
  info = 0;
  if (n == 1){ dlam = d[1] + rho*z[1]*z[1]; DL(1) = 1.0; return; }
  if (n == 2){ dlaed5(i, d, z, delta, dst, rho, dlam); return; }
  const double eps = EPSD;
  double rhoinv = 1.0/rho;

  if (i == n){
    int ii = n - 1;
    double midpt = rho/2.0;
    for (int j = 1; j <= n; j++) DL(j) = (d[j] - d[i]) - midpt;
    double psi = 0.0;
    for (int j = 1; j <= n-2; j++) psi += z[j]*z[j]/DL(j);
    double c = rhoinv + psi;
    double w = c + z[ii]*z[ii]/DL(ii) + z[n]*z[n]/DL(n);
    double tau, dltlb, dltub;
    if (w <= 0.0){
      double temp = z[n-1]*z[n-1]/(d[n]-d[n-1]+rho) + z[n]*z[n]/rho;
      if (c <= temp) tau = rho;
      else {
        double del = d[n] - d[n-1];
        double a = -c*del + z[n-1]*z[n-1] + z[n]*z[n];
        double b = z[n]*z[n]*del;
        if (a < 0.0) tau = 2.0*b/(sqrt(a*a + 4.0*b*c) - a);
        else tau = (a + sqrt(a*a + 4.0*b*c))/(2.0*c);
      }
      dltlb = midpt; dltub = rho;
    } else {
      double del = d[n] - d[n-1];
      double a = -c*del + z[n-1]*z[n-1] + z[n]*z[n];
      double b = z[n]*z[n]*del;
      if (a < 0.0) tau = 2.0*b/(sqrt(a*a + 4.0*b*c) - a);
      else tau = (a + sqrt(a*a + 4.0*b*c))/(2.0*c);
      dltlb = 0.0; dltub = midpt;
    }
    for (int j = 1; j <= n; j++) DL(j) = (d[j] - d[i]) - tau;
    double dpsi = 0.0, erretm = 0.0; psi = 0.0;
    for (int j = 1; j <= ii; j++){
      double t2 = z[j]/DL(j);
      psi += z[j]*t2; dpsi += t2*t2; erretm += psi;
    }
    erretm = fabs(erretm);
    double temp = z[n]/DL(n);
    double phi = z[n]*temp, dphi = temp*temp;
    erretm = 8.0*(-phi - psi) + erretm - phi + rhoinv + fabs(tau)*(dpsi + dphi);
    w = rhoinv + phi + psi;
    if (fabs(w) <= eps*erretm){ dlam = d[i] + tau; return; }
    if (w <= 0.0) dltlb = fmax(dltlb, tau); else dltub = fmin(dltub, tau);
    c = w - DL(n-1)*dpsi - DL(n)*dphi;
    double a = (DL(n-1) + DL(n))*w - DL(n-1)*DL(n)*(dpsi + dphi);
    double b = DL(n-1)*DL(n)*w;
    if (c < 0.0) c = fabs(c);
    double eta;
    if (c == 0.0) eta = dltub - tau;
    else if (a >= 0.0) eta = (a + sqrt(fabs(a*a - 4.0*b*c)))/(2.0*c);
    else eta = 2.0*b/(a - sqrt(fabs(a*a - 4.0*b*c)));
    if (w*eta > 0.0) eta = -w/(dpsi + dphi);
    temp = tau + eta;
    if (temp > dltub || temp < dltlb){
      if (w < 0.0) eta = (dltub - tau)/2.0; else eta = (dltlb - tau)/2.0;
    }
    for (int j = 1; j <= n; j++) DL(j) -= eta;
    tau += eta;
    dpsi = 0.0; psi = 0.0; erretm = 0.0;
    for (int j = 1; j <= ii; j++){
      double t2 = z[j]/DL(j);
      psi += z[j]*t2; dpsi += t2*t2; erretm += psi;
    }
    erretm = fabs(erretm);
    temp = z[n]/DL(n);
    phi = z[n]*temp; dphi = temp*temp;
    erretm = 8.0*(-phi - psi) + erretm - phi + rhoinv + fabs(tau)*(dpsi + dphi);
    w = rhoinv + phi + psi;
    for (int it = 3; it <= maxit; it++){
      if (fabs(w) <= eps*erretm){ dlam = d[i] + tau; return; }
      if (w <= 0.0) dltlb = fmax(dltlb, tau); else dltub = fmin(dltub, tau);
      c = w - DL(n-1)*dpsi - DL(n)*dphi;
      a = (DL(n-1) + DL(n))*w - DL(n-1)*DL(n)*(dpsi + dphi);
      b = DL(n-1)*DL(n)*w;
      if (a >= 0.0) eta = (a + sqrt(fabs(a*a - 4.0*b*c)))/(2.0*c);
      else eta = 2.0*b/(a - sqrt(fabs(a*a - 4.0*b*c)));
      if (w*eta > 0.0) eta = -w/(dpsi + dphi);
      temp = tau + eta;
      if (temp > dltub || temp < dltlb){
        if (w < 0.0) eta = (dltub - tau)/2.0; else eta = (dltlb - tau)/2.0;
      }
      for (int j = 1; j <= n; j++) DL(j) -= eta;
      tau += eta;
      dpsi = 0.0; psi = 0.0; erretm = 0.0;
      for (int j = 1; j <= ii; j++){
        double t2 = z[j]/DL(j);
        psi += z[j]*t2; dpsi += t2*t2; erretm += psi;
      }
      erretm = fabs(erretm);
      temp = z[n]/DL(n);
      phi = z[n]*temp; dphi = temp*temp;
      erretm = 8.0*(-phi - psi) + erretm - phi + rhoinv + fabs(tau)*(dpsi + dphi);
      w = rhoinv + phi + psi;
    }
    info = 1; dlam = d[i] + tau; return;
  }

  {
    int ip1 = i + 1;
    double del = d[ip1] - d[i];
    double midpt = del/2.0;
    for (int j = 1; j <= n; j++) DL(j) = (d[j] - d[i]) - midpt;
    double psi = 0.0;
    for (int j = 1; j <= i-1; j++) psi += z[j]*z[j]/DL(j);
    double phi = 0.0;
    for (int j = n; j >= i+2; j--) phi += z[j]*z[j]/DL(j);
    double c = rhoinv + psi + phi;
    double w = c + z[i]*z[i]/DL(i) + z[ip1]*z[ip1]/DL(ip1);
    bool orgati;
    double tau, dltlb, dltub;
    if (w > 0.0){
      orgati = true;
      double a = c*del + z[i]*z[i] + z[ip1]*z[ip1];
      double b = z[i]*z[i]*del;
      if (a > 0.0) tau = 2.0*b/(a + sqrt(fabs(a*a - 4.0*b*c)));
      else tau = (a - sqrt(fabs(a*a - 4.0*b*c)))/(2.0*c);
      dltlb = 0.0; dltub = midpt;
    } else {
      orgati = false;
      double a = c*del - z[i]*z[i] - z[ip1]*z[ip1];
      double b = z[ip1]*z[ip1]*del;
      if (a < 0.0) tau = 2.0*b/(a - sqrt(fabs(a*a + 4.0*b*c)));
      else tau = -(a + sqrt(fabs(a*a + 4.0*b*c)))/(2.0*c);
      dltlb = -midpt; dltub = 0.0;
    }
    if (orgati){ for (int j = 1; j <= n; j++) DL(j) = (d[j] - d[i]) - tau; }
    else { for (int j = 1; j <= n; j++) DL(j) = (d[j] - d[ip1]) - tau; }
    int ii = orgati ? i : i+1;
    int iim1 = ii - 1, iip1 = ii + 1;
    double dpsi = 0.0, erretm = 0.0; psi = 0.0;
    for (int j = 1; j <= iim1; j++){
      double t2 = z[j]/DL(j);
      psi += z[j]*t2; dpsi += t2*t2; erretm += psi;
    }
    erretm = fabs(erretm);
    double dphi = 0.0; phi = 0.0;
    for (int j = n; j >= iip1; j--){
      double t2 = z[j]/DL(j);
      phi += z[j]*t2; dphi += t2*t2; erretm += phi;
    }
    w = rhoinv + phi + psi;
    bool swtch3 = false;
    if (orgati){ if (w < 0.0) swtch3 = true; }
    else { if (w > 0.0) swtch3 = true; }
    if (ii == 1 || ii == n) swtch3 = false;
    double temp = z[ii]/DL(ii);
    double dw = dpsi + dphi + temp*temp;
    temp = z[ii]*temp;
    w += temp;
    erretm = 8.0*(phi - psi) + erretm + 2.0*rhoinv + 3.0*fabs(temp) + fabs(tau)*dw;
    if (fabs(w) <= eps*erretm){ dlam = (orgati ? d[i] : d[ip1]) + tau; return; }
    if (w <= 0.0) dltlb = fmax(dltlb, tau); else dltub = fmin(dltub, tau);
    double eta;
    double zz[4];
    if (!swtch3){
      double cc;
      if (orgati) cc = w - DL(ip1)*dw - (d[i]-d[ip1])*(z[i]/DL(i))*(z[i]/DL(i));
      else cc = w - DL(i)*dw - (d[ip1]-d[i])*(z[ip1]/DL(ip1))*(z[ip1]/DL(ip1));
      double a = (DL(i) + DL(ip1))*w - DL(i)*DL(ip1)*dw;
      double b = DL(i)*DL(ip1)*w;
      if (cc == 0.0){
        if (a == 0.0){
          if (orgati) a = z[i]*z[i] + DL(ip1)*DL(ip1)*(dpsi + dphi);
          else a = z[ip1]*z[ip1] + DL(i)*DL(i)*(dpsi + dphi);
        }
        eta = b/a;
      } else if (a <= 0.0) eta = (a - sqrt(fabs(a*a - 4.0*b*cc)))/(2.0*cc);
      else eta = 2.0*b/(a + sqrt(fabs(a*a - 4.0*b*cc)));
    } else {
      double tempc = rhoinv + psi + phi;
      double cc;
      if (orgati){
        double temp1 = z[iim1]/DL(iim1);
        temp1 = temp1*temp1;
        cc = tempc - DL(iip1)*(dpsi + dphi) - (d[iim1]-d[iip1])*temp1;
        zz[1] = z[iim1]*z[iim1];
        zz[3] = DL(iip1)*DL(iip1)*((dpsi - temp1) + dphi);
      } else {
        double temp1 = z[iip1]/DL(iip1);
        temp1 = temp1*temp1;
        cc = tempc - DL(iim1)*(dpsi + dphi) - (d[iip1]-d[iim1])*temp1;
        zz[1] = DL(iim1)*DL(iim1)*(dpsi + (dphi - temp1));
        zz[3] = z[iip1]*z[iip1];
      }
      zz[2] = z[ii]*z[ii];
      double dd3[4];
      dd3[1] = DL(iim1); dd3[2] = DL(ii); dd3[3] = DL(iip1);
      int info6;
      dlaed6(2, orgati, cc, dd3, zz, w, eta, info6);
      if (info6 != 0){ info = 1; dlam = (orgati ? d[i] : d[ip1]) + tau; return; }
    }
    if (w*eta >= 0.0) eta = -w/dw;
    temp = tau + eta;
    if (temp > dltub || temp < dltlb){
      if (w < 0.0) eta = (dltub - tau)/2.0; else eta = (dltlb - tau)/2.0;
    }
    double prew = w;
    for (int j = 1; j <= n; j++) DL(j) -= eta;
    tau += eta;
    dpsi = 0.0; psi = 0.0; erretm = 0.0;
    for (int j = 1; j <= iim1; j++){
      double t2 = z[j]/DL(j);
      psi += z[j]*t2; dpsi += t2*t2; erretm += psi;
    }
    erretm = fabs(erretm);
    dphi = 0.0; phi = 0.0;
    for (int j = n; j >= iip1; j--){
      double t2 = z[j]/DL(j);
      phi += z[j]*t2; dphi += t2*t2; erretm += phi;
    }
    temp = z[ii]/DL(ii);
    dw = dpsi + dphi + temp*temp;
    temp = z[ii]*temp;
    w = rhoinv + phi + psi + temp;
    erretm = 8.0*(phi - psi) + erretm + 2.0*rhoinv + 3.0*fabs(temp) + fabs(tau)*dw;
    bool swtch = false;
    if (orgati){ if (-w > fabs(prew)/10.0) swtch = true; }
    else { if (w > fabs(prew)/10.0) swtch = true; }
    for (int it = 3; it <= maxit; it++){
      if (fabs(w) <= eps*erretm){ dlam = (orgati ? d[i] : d[ip1]) + tau; return; }
      if (w <= 0.0) dltlb = fmax(dltlb, tau); else dltub = fmin(dltub, tau);
      if (!swtch3){
        double cc;
        if (!swtch){
          if (orgati) cc = w - DL(ip1)*dw - (d[i]-d[ip1])*(z[i]/DL(i))*(z[i]/DL(i));
          else cc = w - DL(i)*dw - (d[ip1]-d[i])*(z[ip1]/DL(ip1))*(z[ip1]/DL(ip1));
        } else {
          double t2 = z[ii]/DL(ii);
          if (orgati) dpsi += t2*t2;
          else dphi += t2*t2;
          cc = w - DL(i)*dpsi - DL(ip1)*dphi;
        }
        double a = (DL(i) + DL(ip1))*w - DL(i)*DL(ip1)*dw;
        double b = DL(i)*DL(ip1)*w;
        if (cc == 0.0){
          if (a == 0.0){
            if (!swtch){
              if (orgati) a = z[i]*z[i] + DL(ip1)*DL(ip1)*(dpsi + dphi);
              else a = z[ip1]*z[ip1] + DL(i)*DL(i)*(dpsi + dphi);
            } else {
              a = DL(i)*DL(i)*dpsi + DL(ip1)*DL(ip1)*dphi;
            }
          }
          eta = b/a;
        } else if (a <= 0.0) eta = (a - sqrt(fabs(a*a - 4.0*b*cc)))/(2.0*cc);
        else eta = 2.0*b/(a + sqrt(fabs(a*a - 4.0*b*cc)));
      } else {
        double tempc = rhoinv + psi + phi;
        double cc;
        if (swtch){
          cc = tempc - DL(iim1)*dpsi - DL(iip1)*dphi;
          zz[1] = DL(iim1)*DL(iim1)*dpsi;
          zz[3] = DL(iip1)*DL(iip1)*dphi;
        } else {
          if (orgati){
            double temp1 = z[iim1]/DL(iim1);
            temp1 = temp1*temp1;
            cc = tempc - DL(iip1)*(dpsi + dphi) - (d[iim1]-d[iip1])*temp1;
            zz[1] = z[iim1]*z[iim1];
            zz[3] = DL(iip1)*DL(iip1)*((dpsi - temp1) + dphi);
          } else {
            double temp1 = z[iip1]/DL(iip1);
            temp1 = temp1*temp1;
            cc = tempc - DL(iim1)*(dpsi + dphi) - (d[iip1]-d[iim1])*temp1;
            zz[1] = DL(iim1)*DL(iim1)*(dpsi + (dphi - temp1));
            zz[3] = z[iip1]*z[iip1];
          }
          zz[2] = z[ii]*z[ii];
        }
        double dd3[4];
        dd3[1] = DL(iim1); dd3[2] = DL(ii); dd3[3] = DL(iip1);
        int info6;
        dlaed6(it, orgati, cc, dd3, zz, w, eta, info6);
        if (info6 != 0){ info = 1; dlam = (orgati ? d[i] : d[ip1]) + tau; return; }
      }
      if (w*eta >= 0.0) eta = -w/dw;
      temp = tau + eta;
      if (temp > dltub || temp < dltlb){
        if (w < 0.0) eta = (dltub - tau)/2.0; else eta = (dltlb - tau)/2.0;
      }
      for (int j = 1; j <= n; j++) DL(j) -= eta;
      tau += eta;
      prew = w;
      dpsi = 0.0; psi = 0.0; erretm = 0.0;
      for (int j = 1; j <= iim1; j++){
        double t2 = z[j]/DL(j);
        psi += z[j]*t2; dpsi += t2*t2; erretm += psi;
      }
      erretm = fabs(erretm);
      dphi = 0.0; phi = 0.0;
      for (int j = n; j >= iip1; j--){
        double t2 = z[j]/DL(j);
        phi += z[j]*t2; dphi += t2*t2; erretm += phi;
      }
      temp = z[ii]/DL(ii);
      dw = dpsi + dphi + temp*temp;
      temp = z[ii]*temp;
      w = rhoinv + phi + psi + temp;
      erretm = 8.0*(phi - psi) + erretm + 2.0*rhoinv + 3.0*fabs(temp) + fabs(tau)*dw;
      if (w*prew > 0.0 && fabs(w) > fabs(prew)/10.0) swtch = !swtch;
    }
    info = 1; dlam = (orgati ? d[i] : d[ip1]) + tau; return;
  }
#undef DL
}

// ======================= dlaed2 scan (scalar only; records rotations) =======================
__device__ void dlaed2_scan(int& kOut, int n, int n1, double* d, int* indxq, double& rho,
    double* z, double* dlamda, double* w,
    int* indx, int* indxc, int* indxp, int* coltyp,
    int* rotp, int* rotn, double* rotc, double* rots, int& nrot,
    int* ctot, int& deflall){
  nrot = 0; deflall = 0;
  int n2 = n - n1, n1p1 = n1 + 1;
  if (rho < 0.0){ for (int j = n1p1; j <= n; j++) z[j] = -z[j]; }
  double tscal = 1.0/sqrt(2.0);
  for (int j = 1; j <= n; j++) z[j] *= tscal;
  rho = fabs(2.0*rho);
  for (int i = n1p1; i <= n; i++) indxq[i] += n1;
  for (int i = 1; i <= n; i++) dlamda[i] = d[indxq[i]];
  dlamrg(n1, n2, dlamda, 1, 1, indxc);
  for (int i = 1; i <= n; i++) indx[i] = indxq[indxc[i]];
  int imax = 1, jmax = 1;
  for (int j = 2; j <= n; j++) if (fabs(z[j]) > fabs(z[imax])) imax = j;
  for (int j = 2; j <= n; j++) if (fabs(d[j]) > fabs(d[jmax])) jmax = j;
  double tol = 8.0*EPSD*fmax(fabs(d[jmax]), fabs(z[imax]));
  if (rho*fabs(z[imax]) <= tol){
    kOut = 0; deflall = 1;
    for (int j = 1; j <= n; j++) dlamda[j] = d[indx[j]];
    ctot[1] = ctot[2] = ctot[3] = ctot[4] = 0;
    return;
  }
  for (int i = 1; i <= n1; i++) coltyp[i] = 1;
  for (int i = n1p1; i <= n; i++) coltyp[i] = 3;
  int k = 0, k2 = n + 1;
  int pj = 0, nj = 0, j = 0;
  bool allDone = false;
  for (j = 1; j <= n; j++){
    nj = indx[j];
    if (rho*fabs(z[nj]) <= tol){
      k2--; coltyp[nj] = 4; indxp[k2] = nj;
      if (j == n) allDone = true;
    } else { pj = nj; break; }
  }
  if (!allDone){
    while (true){
      j++;
      if (j > n) break;
      nj = indx[j];
      if (rho*fabs(z[nj]) <= tol){
        k2--; coltyp[nj] = 4; indxp[k2] = nj;
      } else {
        double sN = z[pj], cN = z[nj];
        double tau2 = dlapy2(cN, sN);
        double tdif = d[nj] - d[pj];
        cN = cN/tau2; sN = -sN/tau2;
        if (fabs(tdif*cN*sN) <= tol){
          z[nj] = tau2; z[pj] = 0.0;
          if (coltyp[nj] != coltyp[pj]) coltyp[nj] = 2;
          coltyp[pj] = 4;
          nrot++;
          rotp[nrot] = pj; rotn[nrot] = nj; rotc[nrot] = cN; rots[nrot] = sN;
          double tq = d[pj]*cN*cN + d[nj]*sN*sN;
          d[nj] = d[pj]*sN*sN + d[nj]*cN*cN;
          d[pj] = tq;
          k2--;
          int i2 = 1;
          while (true){
            if (k2 + i2 <= n){
              if (d[pj] < d[indxp[k2+i2]]){
                indxp[k2+i2-1] = indxp[k2+i2];
                indxp[k2+i2] = pj;
                i2++;
              } else { indxp[k2+i2-1] = pj; break; }
            } else { indxp[k2+i2-1] = pj; break; }
          }
          pj = nj;
        } else {
          k++; dlamda[k] = d[pj]; w[k] = z[pj]; indxp[k] = pj;
          pj = nj;
        }
      }
    }
    k++; dlamda[k] = d[pj]; w[k] = z[pj]; indxp[k] = pj;
  }
  int ct[5] = {0,0,0,0,0};
  for (int jj = 1; jj <= n; jj++) ct[coltyp[jj]]++;
  int psm[5];
  psm[1] = 1; psm[2] = 1 + ct[1]; psm[3] = psm[2] + ct[2]; psm[4] = psm[3] + ct[3];
  k = n - ct[4];
  for (int jj = 1; jj <= n; jj++){
    int js = indxp[jj];
    int cti = coltyp[js];
    indx[psm[cti]] = js;
    indxc[psm[cti]] = jj;
    psm[cti]++;
  }
  ctot[1] = ct[1]; ctot[2] = ct[2]; ctot[3] = ct[3]; ctot[4] = ct[4];
  kOut = k;
}

// ======================= eig stage 1: tridiagonalization (1024 thr, lower-triangle) ===========
// Matrix is bitwise symmetric (k5_cov product order + IEEE commutativity), so reading
// A[c][r] in place of A[r][c] and updating only the lower triangle is bitwise-identical.
__global__ __launch_bounds__(1024) void eig_tridiag(
    double* __restrict__ covg, double* __restrict__ Vg,
    double* __restrict__ f64g){
  const int mtx = blockIdx.x;
  const int tid = threadIdx.x;     // 0..1023
  const int rp = tid & 255;        // row slot
  const int cp = tid >> 8;         // column chunk 0..3
  const int wid = tid >> 6;        // wave 0..15
  const int lane = tid & 63;
  double* A0 = covg + (size_t)mtx*65536;
  double* Q0 = Vg + (size_t)mtx*65536;
  double* F  = f64g + (size_t)mtx*4096;
  double* d1 = F - 1;
  double* e1 = F + 256 - 1;
  double* tau1 = F + 512 - 1;

  __shared__ double shv[257], shw[257], shp[1024], shpart[16];
  __shared__ double sh_d[4];

  for (int idx = tid; idx < 65536; idx += 1024) Q0[idx] = 0.0;
  __syncthreads();

  for (int i1 = 1; i1 <= NEIG-1; i1++){
    const int nr = NEIG - i1;
    double part = 0.0;
    for (int rr = 1+tid; rr <= nr; rr += 1024){
      double v = A0[(i1+rr-1) + (size_t)(i1-1)*LDQ];   // lower triangle (rows > col i1)
      shv[rr] = v;
      if (rr >= 2) part += v*v;
    }
    for (int o = 32; o > 0; o >>= 1) part += __shfl_down(part, o);
    if (lane == 0) shpart[wid] = part;
    __syncthreads();
    if (tid == 0){
      double xn2 = 0.0;
      for (int w2 = 0; w2 < 16; w2++) xn2 += shpart[w2];
      double alpha = shv[1];
      double taui, scal = 0.0;
      if (xn2 == 0.0){ taui = 0.0; e1[i1] = alpha; }
      else {
        double xnorm = sqrt(xn2);
        double beta = -fsign(dlapy2(alpha, xnorm), alpha);
        taui = (beta - alpha)/beta;
        scal = 1.0/(alpha - beta);
        e1[i1] = beta;
      }
      tau1[i1] = taui;
      sh_d[0] = taui; sh_d[1] = scal;
    }
    __syncthreads();
    double taui = sh_d[0], scal = sh_d[1];
    if (taui != 0.0){
      for (int rr = 1+tid; rr <= nr; rr += 1024){
        if (rr == 1) shv[1] = 1.0;
        else {
          double nv = shv[rr]*scal;
          shv[rr] = nv;
          A0[(i1+rr-1) + (size_t)(i1-1)*LDQ] = nv;     // reflector storage (lower)
        }
      }
      __syncthreads();
      int clen = (nr + 3) >> 2;
      int c0 = cp*clen + 1;
      int c1 = c0 + clen - 1; if (c1 > nr) c1 = nr;
      double pp = 0.0;
      if (rp + 1 <= nr){
        const int lr = rp + 1;
        const double* arow = A0 + (i1+lr-1);                  // + (i1+lc-1)*LDQ : M(lr,lc), lc<=lr
        const double* acol = A0 + (size_t)(i1+lr-1)*LDQ;      // + (i1+lc-1)     : M(lc,lr), lc>lr
        // part 1: lc in [c0, min(c1,lr)] — coalesced across lanes
        int b1 = (c1 < lr) ? c1 : lr;
        for (int lc = c0; lc <= b1; lc++)
          pp += arow[(size_t)(i1+lc-1)*LDQ]*shv[lc];
        // part 2: lc in [max(c0,lr+1), c1] — per-lane contiguous (L1 line-buffered)
        int b2 = (c0 > lr+1) ? c0 : lr+1;
        for (int lc = b2; lc <= c1; lc++)
          pp += acol[(i1+lc-1)]*shv[lc];
      }
      shp[cp*256 + rp] = pp;
      __syncthreads();
      double dotc = 0.0;
      if (tid < 256){
        if (tid + 1 <= nr){
          double acc = ((shp[tid] + shp[256+tid]) + (shp[512+tid] + shp[768+tid]))*taui;
          shw[tid+1] = acc;
          dotc = acc*shv[tid+1];
        }
        for (int o = 32; o > 0; o >>= 1) dotc += __shfl_down(dotc, o);
        if (lane == 0) shpart[wid] = dotc;
      }
      __syncthreads();
      if (tid < 256 && tid + 1 <= nr){
        double alpha2 = -0.5*taui*((shpart[0]+shpart[1])+(shpart[2]+shpart[3]));
        shw[tid+1] += alpha2*shv[tid+1];
      }
      __syncthreads();
      // rank-2 update, lower triangle only (lc <= lr)
      if (rp + 1 <= nr){
        const int lr = rp + 1;
        double vr = shv[lr], wr = shw[lr];
        double* arow = A0 + (i1+lr-1);
        int b1 = (c1 < lr) ? c1 : lr;
        for (int lc = c0; lc <= b1; lc++)
          arow[(size_t)(i1+lc-1)*LDQ] -= vr*shw[lc] + wr*shv[lc];
      }
      __syncthreads();
    }
  }
  for (int j = 1+tid; j <= NEIG; j += 1024) d1[j] = A0[(j-1) + (size_t)(j-1)*LDQ];
  __syncthreads();

  if (tid == 0){
    double mx = 0.0;
    for (int i = 1; i <= NEIG; i++) mx = fmax(mx, fabs(d1[i]));
    for (int i = 1; i <= NEIG-1; i++) mx = fmax(mx, fabs(e1[i]));
    F[3208] = mx;
    double mul = 1.0/mx;
    for (int i = 1; i <= NEIG; i++) d1[i] *= mul;
    for (int i = 1; i <= NEIG-1; i++) e1[i] *= mul;
    for (int i = 1; i <= 15; i++){
      int smm1 = 16*i;
      d1[smm1]   -= fabs(e1[smm1]);
      d1[smm1+1] -= fabs(e1[smm1]);
    }
  }
}

// ======================= eig stage 2: leaves (LDS dsteqr) =======================
__global__ __launch_bounds__(64) void eig_leaves(
    double* __restrict__ Vg, double* __restrict__ f64g, int* __restrict__ i32g){
  const int mtx = blockIdx.x >> 4;
  const int leaf = blockIdx.x & 15;
  const int tid = threadIdx.x;
  double* Q0 = Vg + (size_t)mtx*65536;
  double* F  = f64g + (size_t)mtx*4096;
  int* IA    = i32g + (size_t)mtx*4096;
  const int submat = leaf*16 + 1;  // 1-based

  __shared__ double shd[17], she[17], shwk[40], shZ[256];
  if (tid < 16) shd[tid+1] = F[submat-1 + tid];
  if (tid < 15) she[tid+1] = F[256 + submat-1 + tid];
  __syncthreads();
  if (tid == 0) dsteqr_serial(16, shd, she, shZ, 16, shwk);
  __syncthreads();
  for (int idx = tid; idx < 256; idx += 64){
    int c = idx >> 4, r = idx & 15;
    Q0[(submat-1+r) + (size_t)(submat-1+c)*LDQ] = shZ[r + c*16];
  }
  if (tid < 16){
    F[submat-1+tid] = shd[tid+1];
    IA[submat-1+tid] = tid+1;
  }
}

// ======================= eig stage 3: one D&C merge level =======================
__global__ __launch_bounds__(256) void eig_merge(
    double* __restrict__ Vg, double* __restrict__ q2g, double* __restrict__ sg,
    double* __restrict__ Tg,
    double* __restrict__ f64g, int* __restrict__ i32g, int n, int nmerges){
  const int bid = blockIdx.x;
  const int mtx = bid / nmerges;
  const int mi  = bid % nmerges;
  const int tid = threadIdx.x;
  double* Q0 = Vg + (size_t)mtx*65536;
  double* F  = f64g + (size_t)mtx*4096;
  int* IA    = i32g + (size_t)mtx*4096;
  double* d1 = F - 1;
  double* e1 = F + 256 - 1;
  int* indxqg = IA - 1;
  double* q2a = q2g + (size_t)mtx*65536 + (size_t)mi*n*n;
  double* sa  = sg  + (size_t)mtx*65536 + (size_t)mi*n*n;
  double* Ta  = Tg  + (size_t)mtx*65536 + (size_t)mi*n*n;
  const int s0 = mi*n + 1;
  const int cut = n/2;
#define QG(i,j) Q0[(s0-1 + (i)-1) + (size_t)(s0-1 + (j)-1)*LDQ]
#define TS(i,j) Ta[(size_t)((i)-1)*n + ((j)-1)]

  __shared__ double sd[257], sz[257], sdl[257], sw[257], sst[257], src_[257], srs_[257];
  __shared__ int siq[257], six[257], sic[257], sip[257], sit[257], srp_[257], srn_[257];
  __shared__ int sh_i[8];
  __shared__ double sh_d[2];

  for (int i = 1+tid; i <= n; i += 256){ sd[i] = d1[s0-1+i]; siq[i] = indxqg[s0-1+i]; }
  for (int j = 1+tid; j <= cut; j += 256) sz[j] = QG(cut, j);
  for (int j = cut+1+tid; j <= n; j += 256) sz[j] = QG(cut+1, j);
  __syncthreads();
  if (tid == 0){
    double rho = e1[s0 + cut - 1];
    int kk, nrot, defl;
    dlaed2_scan(kk, n, cut, sd, siq, rho, sz, sdl, sw, six, sic, sip, sit,
                srp_, srn_, src_, srs_, nrot, sh_i, defl);
    sh_i[0] = kk; sh_i[5] = nrot; sh_i[6] = defl; sh_d[0] = rho;
  }
  __syncthreads();
  const int k = sh_i[0];
  const int ct1 = sh_i[1], ct2 = sh_i[2], ct3 = sh_i[3], ct4 = sh_i[4];
  const int nrot = sh_i[5], defl = sh_i[6];
  const double rho = sh_d[0];
  const int nn1 = cut, nn2 = n - cut;

  if (defl){
    for (int idx = tid; idx < n*n; idx += 256){
      int j = idx / n, r = idx % n;
      q2a[idx] = QG(r+1, six[j+1]);
    }
    __syncthreads();
    for (int idx = tid; idx < n*n; idx += 256){
      int j = idx / n, r = idx % n;
      QG(r+1, j+1) = q2a[idx];
    }
    for (int i = 1+tid; i <= n; i += 256){
      d1[s0-1+i] = sdl[i];
      indxqg[s0-1+i] = i;
    }
    return;
  }

  {
    int r = tid + 1;
    if (r <= n){
      for (int t = 1; t <= nrot; t++){
        int pj = srp_[t], nj = srn_[t];
        double c = src_[t], s = srs_[t];
        double xq = QG(r, pj), yq = QG(r, nj);
        QG(r, pj) = c*xq + s*yq;
        QG(r, nj) = c*yq - s*xq;
      }
    }
  }
  __syncthreads();
  for (int i = 1+tid; i <= n; i += 256) sz[i] = sd[six[i]];
  __syncthreads();
  const int iq12 = ct1*nn1;
  const int iq2base = (ct1+ct2)*nn1;
  const int iq2b3 = iq2base + ct2*nn2;
  const int iq2d = iq2b3 + ct3*nn2;
  for (int idx = tid; idx < ct1*nn1; idx += 256){
    int jj = idx / nn1, r = idx % nn1;
    q2a[jj*nn1 + r] = QG(r+1, six[jj+1]);
  }
  for (int idx = tid; idx < ct2*nn1; idx += 256){
    int jj = idx / nn1, r = idx % nn1;
    q2a[iq12 + jj*nn1 + r] = QG(r+1, six[ct1+jj+1]);
  }
  for (int idx = tid; idx < ct2*nn2; idx += 256){
    int jj = idx / nn2, r = idx % nn2;
    q2a[iq2base + jj*nn2 + r] = QG(nn1+r+1, six[ct1+jj+1]);
  }
  for (int idx = tid; idx < ct3*nn2; idx += 256){
    int jj = idx / nn2, r = idx % nn2;
    q2a[iq2b3 + jj*nn2 + r] = QG(nn1+r+1, six[ct1+ct2+jj+1]);
  }
  for (int idx = tid; idx < ct4*n; idx += 256){
    int jj = idx / n, r = idx % n;
    q2a[iq2d + jj*n + r] = QG(r+1, six[ct1+ct2+ct3+jj+1]);
  }
  __syncthreads();
  for (int idx = tid; idx < ct4*n; idx += 256){
    int jj = idx / n, r = idx % n;
    QG(r+1, k+jj+1) = q2a[iq2d + jj*n + r];
  }
  for (int jj = k+1+tid; jj <= n; jj += 256) sd[jj] = sz[jj];
  __syncthreads();
  for (int j = 1+tid; j <= k; j += 256){
    int info; double dj;
    dlaed4(k, j, sdl, sw, Ta + (j-1), n, rho, dj, info);
    sd[j] = dj;
  }
  __syncthreads();
  if (k == 2){
    if (tid == 0){
      for (int j = 1; j <= 2; j++){
        double a1 = TS(1,j), a2 = TS(2,j);
        TS(1,j) = (sic[1] == 1) ? a1 : a2;
        TS(2,j) = (sic[2] == 1) ? a1 : a2;
      }
    }
    __syncthreads();
  } else if (k >= 3){
    for (int i = 1+tid; i <= k; i += 256) sst[i] = sw[i];
    __syncthreads();
    for (int i = 1+tid; i <= k; i += 256){
      double prod = TS(i,i);
      for (int j2 = 1; j2 < i; j2++) prod *= TS(i,j2)/(sdl[i] - sdl[j2]);
      for (int j2 = i+1; j2 <= k; j2++) prod *= TS(i,j2)/(sdl[i] - sdl[j2]);
      sw[i] = fsign(sqrt(-prod), sst[i]);
    }
    __syncthreads();
    for (int j2 = 1+tid; j2 <= k; j2 += 256){
      double nrm = 0.0;
      for (int i = 1; i <= k; i++){
        double v = sw[i]/TS(i,j2);
        sa[(size_t)(i-1)*n + (j2-1)] = v;
        nrm += v*v;
      }
      nrm = sqrt(nrm);
      for (int i = 1; i <= k; i++) TS(i,j2) = sa[(size_t)(sic[i]-1)*n + (j2-1)]/nrm;
    }
    __syncthreads();
  }
  {
    const int n12 = ct1 + ct2, n23 = ct2 + ct3;
    const size_t iq2 = (size_t)nn1*n12;
    const int kf = k & ~7;
    const int njb = kf >> 3;
    for (int idx = tid; idx < njb*nn2; idx += 256){
      int jb = idx / nn2, r = idx % nn2;
      int j2b = jb << 3;
      double a0=0,a1=0,a2=0,a3=0,a4=0,a5=0,a6=0,a7=0;
      const double* qp = q2a + iq2 + r;
      const double* tp = Ta + (size_t)ct1*n + j2b;
      for (int t2 = 0; t2 < n23; t2++){
        double q = qp[(size_t)t2*nn2];
        const double* tr = tp + (size_t)t2*n;
        a0 += q*tr[0]; a1 += q*tr[1]; a2 += q*tr[2]; a3 += q*tr[3];
        a4 += q*tr[4]; a5 += q*tr[5]; a6 += q*tr[6]; a7 += q*tr[7];
      }
      double* og = Q0 + (s0-1 + nn1 + r) + (size_t)(s0-1 + j2b)*LDQ;
      og[0] = a0; og[(size_t)1*LDQ] = a1; og[(size_t)2*LDQ] = a2; og[(size_t)3*LDQ] = a3;
      og[(size_t)4*LDQ] = a4; og[(size_t)5*LDQ] = a5; og[(size_t)6*LDQ] = a6; og[(size_t)7*LDQ] = a7;
    }
    for (int idx = tid; idx < (k-kf)*nn2; idx += 256){
      int j2 = kf + idx / nn2, r = idx % nn2;
      double acc = 0.0;
      for (int t2 = 0; t2 < n23; t2++)
        acc += q2a[iq2 + (size_t)t2*nn2 + r] * TS(ct1 + t2 + 1, j2 + 1);
      QG(nn1 + r + 1, j2 + 1) = acc;
    }
    for (int idx = tid; idx < njb*nn1; idx += 256){
      int jb = idx / nn1, r = idx % nn1;
      int j2b = jb << 3;
      double a0=0,a1=0,a2=0,a3=0,a4=0,a5=0,a6=0,a7=0;
      const double* qp = q2a + r;
      const double* tp = Ta + j2b;
      for (int t2 = 0; t2 < n12; t2++){
        double q = qp[(size_t)t2*nn1];
        const double* tr = tp + (size_t)t2*n;
        a0 += q*tr[0]; a1 += q*tr[1]; a2 += q*tr[2]; a3 += q*tr[3];
        a4 += q*tr[4]; a5 += q*tr[5]; a6 += q*tr[6]; a7 += q*tr[7];
      }
      double* og = Q0 + (s0-1 + r) + (size_t)(s0-1 + j2b)*LDQ;
      og[0] = a0; og[(size_t)1*LDQ] = a1; og[(size_t)2*LDQ] = a2; og[(size_t)3*LDQ] = a3;
      og[(size_t)4*LDQ] = a4; og[(size_t)5*LDQ] = a5; og[(size_t)6*LDQ] = a6; og[(size_t)7*LDQ] = a7;
    }
    for (int idx = tid; idx < (k-kf)*nn1; idx += 256){
      int j2 = kf + idx / nn1, r = idx % nn1;
      double acc = 0.0;
      for (int t2 = 0; t2 < n12; t2++)
        acc += q2a[(size_t)t2*nn1 + r] * TS(t2 + 1, j2 + 1);
      QG(r + 1, j2 + 1) = acc;
    }
    __syncthreads();
  }
  if (tid == 0) dlamrg(k, n - k, sd, 1, -1, siq);
  __syncthreads();
  for (int i = 1+tid; i <= n; i += 256){
    d1[s0-1+i] = sd[i];
    indxqg[s0-1+i] = siq[i];
  }
#undef QG
#undef TS
}

// ======================= eig stage 4a: permute columns + d =======================
__global__ __launch_bounds__(256) void eig_perm(
    double* __restrict__ Vg, double* __restrict__ sg,
    double* __restrict__ f64g, const int* __restrict__ i32g){
  const int mtx = blockIdx.x;
  const int tid = threadIdx.x;
  double* Q0 = Vg + (size_t)mtx*65536;
  double* sa = sg + (size_t)mtx*65536;
  double* F  = f64g + (size_t)mtx*4096;
  const int* IA = i32g + (size_t)mtx*4096;
  __shared__ double shd[256];

  for (int idx = tid; idx < 65536; idx += 256){
    int jc = idx >> 8;
    int r = idx & 255;
    int srcc = IA[jc];
    sa[idx] = Q0[r + (size_t)(srcc-1)*LDQ];
  }
  if (tid == 0){
    double orgnrm = F[3208];
    for (int i = 0; i < 256; i++) shd[i] = F[IA[i]-1]*orgnrm;
  }
  __syncthreads();
  F[tid] = shd[tid];
}

// ======================= eig stage 4b: back-transform (LDS columns, 4-acc dot) =================
__global__ __launch_bounds__(64) void eig_bt(
    const double* __restrict__ covg, const double* __restrict__ sg,
    double* __restrict__ Vg, const double* __restrict__ f64g){
  extern __shared__ double lds[];
  const int mtx = blockIdx.x >> 2;
  const int grp = blockIdx.x & 3;
  const int tid = threadIdx.x;
  const double* A0 = covg + (size_t)mtx*65536;
  const double* sa = sg + (size_t)mtx*65536 + (size_t)grp*64*LDQ;
  double* Qo = Vg + (size_t)mtx*65536 + (size_t)grp*64*LDQ;
  const double* tau1 = f64g + (size_t)mtx*4096 + 512 - 1;

  for (int j = 0; j < 64; j++){
    const double* src = sa + (size_t)j*LDQ;
    double* dstc = lds + (size_t)j*257;
    for (int r = tid; r < 256; r += 64) dstc[r] = src[r];
  }
  __syncthreads();
  double* col = lds + (size_t)tid*257;
  for (int i1 = NEIG-1; i1 >= 1; i1--){
    double ti = tau1[i1];
    if (ti == 0.0) continue;
    const double* av = A0 + (size_t)(i1-1)*LDQ;
    double s0 = 0.0, s1 = 0.0, s2 = 0.0, s3 = 0.0;
    int r = i1+1;
    for (; r + 3 < NEIG; r += 4){
      s0 += av[r]*col[r];
      s1 += av[r+1]*col[r+1];
      s2 += av[r+2]*col[r+2];
      s3 += av[r+3]*col[r+3];
    }
    for (; r < NEIG; r++) s0 += av[r]*col[r];
    double s = (col[i1] + ((s0+s1)+(s2+s3)))*ti;
    col[i1] -= s;
    for (int r2 = i1+1; r2 < NEIG; r2++) col[r2] -= s*av[r2];
  }
  __syncthreads();
  for (int j = 0; j < 64; j++){
    double* dst = Qo + (size_t)j*LDQ;
    const double* srcc = lds + (size_t)j*257;
    for (int r = tid; r < 256; r += 64) dst[r] = srcc[r];
  }
}

// ======================= pipeline kernels =======================
__global__ __launch_bounds__(256) void k1_qkv(const float* __restrict__ x, const float* __restrict__ wqkv,
                                              float* __restrict__ qkvb){
  int idx = blockIdx.x*256 + threadIdx.x;
  if (idx >= 2*48*65536) return;
  int pix = idx & 65535;
  int o = (idx >> 16) % 48;
  int b = idx / (48*65536);
  const float* xb = x + (size_t)b*16*65536 + pix;
  const float* wr = wqkv + o*16;
  float acc = 0.f;
#pragma unroll
  for (int c = 0; c < 16; c++) acc += wr[c]*xb[(size_t)c*65536];
  qkvb[idx] = acc;
}

__global__ __launch_bounds__(256) void k2_dw_patch(const float* __restrict__ qkvb, const float* __restrict__ wdw,
                                                   float* __restrict__ pq, float* __restrict__ pk, float* __restrict__ pv){
  int idx = blockIdx.x*256 + threadIdx.x;
  if (idx >= 2*48*65536) return;
  int j = idx & 255, i = (idx >> 8) & 255;
  int o = (idx >> 16) % 48, b = idx / (48*65536);
  const float* base = qkvb + ((size_t)(b*48 + o) << 16);
  const float* w9 = wdw + o*9;
  float acc = 0.f;
  for (int di = 0; di < 3; di++){
    int ii = i + di - 1;
    if (ii < 0 || ii > 255) continue;
    for (int dj = 0; dj < 3; dj++){
      int jj = j + dj - 1;
      if (jj < 0 || jj > 255) continue;
      acc += w9[di*3+dj]*base[(ii << 8) + jj];
    }
  }
  int part = o / 16, c16 = o % 16;
  int h = c16 >> 2, ch = c16 & 3;
  int m = ((b*4 + h) << 2) + ch;
  int p = ((i >> 4) << 4) + (j >> 4);
  int dd = ((i & 15) << 4) + (j & 15);
  float* dst = (part == 0) ? pq : (part == 1) ? pk : pv;
  dst[((size_t)m << 16) + (p << 8) + dd] = acc;
}

__global__ __launch_bounds__(256) void k3_norms(const float* __restrict__ pq, const float* __restrict__ pk,
                                                double* __restrict__ f64a){
  int m = blockIdx.x;
  int n = threadIdx.x;
  const float* qrow = pq + ((size_t)m << 16) + (n << 8);
  const float* krow = pk + ((size_t)m << 16) + (n << 8);
  double sq = 0.0, sk = 0.0;
  for (int dd = 0; dd < 256; dd++){
    double a = (double)qrow[dd]; sq += a*a;
    double bb = (double)krow[dd]; sk += bb*bb;
  }
  double* F = f64a + (size_t)m*4096;
  F[2688 + n] = fmax(sqrt(sq), 1e-12);
  F[2944 + n] = fmax(sqrt(sk), 1e-12);
}

__global__ __launch_bounds__(256) void k4_attn(const float* __restrict__ pq, const float* __restrict__ pk,
                                               const float* __restrict__ temp4, const double* __restrict__ f64a,
                                               double* __restrict__ xc){
  int m = blockIdx.x >> 8;
  int n = blockIdx.x & 255;
  int t = threadIdx.x;
  __shared__ float qrow[256];
  __shared__ double red[256];
  qrow[t] = pq[((size_t)m << 16) + (n << 8) + t];
  __syncthreads();
  const double* F = f64a + (size_t)m*4096;
  double qn = F[2688 + n], kn = F[2944 + t];
  const float* krow = pk + ((size_t)m << 16) + (t << 8);
  double s = 0.0;
  for (int dd = 0; dd < 256; dd++) s += (double)qrow[dd]*(double)krow[dd];
  int ch = m & 3;
  s = s/(qn*kn)*(double)temp4[ch];
  red[t] = s; __syncthreads();
  for (int st = 128; st > 0; st >>= 1){ if (t < st) red[t] = fmax(red[t], red[t+st]); __syncthreads(); }
  double mx = red[0]; __syncthreads();
  double ev = exp(s - mx);
  red[t] = ev; __syncthreads();
  for (int st = 128; st > 0; st >>= 1){ if (t < st) red[t] += red[t+st]; __syncthreads(); }
  double sum = red[0]; __syncthreads();
  double p = ev/sum;
  red[t] = p; __syncthreads();
  for (int st = 128; st > 0; st >>= 1){ if (t < st) red[t] += red[t+st]; __syncthreads(); }
  double mean = red[0]/256.0;
  xc[((size_t)m << 16) + (n << 8) + t] = p - mean;
}

__global__ __launch_bounds__(256) void k5_cov(const double* __restrict__ xc, double* __restrict__ cov){
  int m = blockIdx.x >> 8, i = blockIdx.x & 255, j = threadIdx.x;
  __shared__ double xi[256];
  const double* base = xc + ((size_t)m << 16);
  xi[j] = base[(i << 8) + j];
  __syncthreads();
  const double* xj = base + (j << 8);
  double acc = 0.0;
  for (int dd = 0; dd < 256; dd++) acc += xi[dd]*xj[dd];
  cov[((size_t)m << 16) + (size_t)j*256 + i] = acc/255.0;  // col-major (i,j)
}

__global__ __launch_bounds__(256) void k5b_trace(const double* __restrict__ cov, double* __restrict__ f64a){
  int m = blockIdx.x, t = threadIdx.x;
  __shared__ double red[256];
  red[t] = cov[((size_t)m << 16) + (size_t)t*257];
  __syncthreads();
  for (int st = 128; st > 0; st >>= 1){ if (t < st) red[t] += red[t+st]; __syncthreads(); }
  if (t == 0) f64a[(size_t)m*4096 + 3200] = red[0];
}

__global__ __launch_bounds__(256) void k5c_scale(double* __restrict__ cov, const double* __restrict__ f64a){
  size_t idx = (size_t)blockIdx.x*256 + threadIdx.x;
  int m = (int)(idx >> 16);
  int e = (int)(idx & 65535);
  double tra = f64a[(size_t)m*4096 + 3200];
  double v = cov[idx]/tra;
  if ((e & 255) == (e >> 8)) v += 1e-5;
  cov[idx] = v;
}

// ======================= tail kernels =======================
__global__ __launch_bounds__(256) void k7_y(const double* __restrict__ V, const float* __restrict__ wfr,
                                            double* __restrict__ Y, double* __restrict__ Yt){
  int m = blockIdx.x >> 8, n = blockIdx.x & 255, p = threadIdx.x;
  if (p >= 100) return;
  const double* Vm = V + ((size_t)m << 16);
  const float* wr = wfr + p*100;
  double acc = 0.0;
  for (int q = 0; q < 100; q++) acc += Vm[n + ((size_t)(255 - q) << 8)]*(double)wr[q];
  Y[(((size_t)m << 8) + n)*128 + p] = acc;
  Yt[(((size_t)m << 7) + p)*256 + n] = acc;
}

__global__ __launch_bounds__(256) void k8_a(const double* __restrict__ Y, const double* __restrict__ Yt,
                                            double* __restrict__ A){
  int m = blockIdx.x >> 8, n = blockIdx.x & 255, j = threadIdx.x;
  const double* yn = Y + (((size_t)m << 8) + n)*128;
  const double* ytb = Yt + ((size_t)m << 7)*256 + j;
  double acc = 0.0;
  for (int p = 0; p < 100; p++) acc += yn[p]*ytb[(size_t)p*256];
  A[((size_t)m << 16) + (n << 8) + j] = acc;
}

__global__ __launch_bounds__(256) void k9_av(const double* __restrict__ A, const float* __restrict__ pv,
                                             float* __restrict__ out1){
  int m = blockIdx.x >> 8, n = blockIdx.x & 255, dd = threadIdx.x;
  __shared__ double arow[256];
  arow[dd] = A[((size_t)m << 16) + (n << 8) + dd];
  __syncthreads();
  const float* vb = pv + ((size_t)m << 16);
  double acc = 0.0;
  for (int mm = 0; mm < 256; mm++) acc += arow[mm]*(double)vb[(mm << 8) + dd];
  out1[((size_t)m << 16) + (n << 8) + dd] = (float)acc;
}

__global__ __launch_bounds__(256) void k10_final(const float* __restrict__ out1, const float* __restrict__ wpo,
                                                 float* __restrict__ out){
  int idx = blockIdx.x*256 + threadIdx.x;
  if (idx >= 2*16*65536) return;
  int d2 = idx & 255, p2 = (idx >> 8) & 255;
  int o = (idx >> 16) & 15, b = idx >> 20;
  int n1 = ((p2 >> 4) << 4) + (d2 >> 4);
  int dold = ((p2 & 15) << 4) + (d2 & 15);
  const float* wr = wpo + o*16;
  float acc = 0.f;
  for (int c = 0; c < 16; c++){
    int h = c >> 2, ch = c & 3;
    int m = ((b*4 + h) << 2) + ch;
    acc += wr[c]*out1[((size_t)m << 16) + (n1 << 8) + dold];
  }
  out[idx] = acc;
}

// ======================= host launcher =======================
extern "C" void kernel_launch(void* const* d_in, const int* in_sizes, int n_in,
                              void* d_out, int out_size, void* d_ws, size_t ws_size,
                              hipStream_t stream){
  const float* x = (const float*)d_in[0];
  const float* w_qkv = (const float*)d_in[1];
  const float* w_dw = (const float*)d_in[2];
  const float* temperature = (const float*)d_in[3];
  const float* w_fr = (const float*)d_in[4];
  const float* w_po = (const float*)d_in[5];
  float* out = (float*)d_out;

  char* ws = (char*)d_ws;
  size_t off = 0;
  auto alloc = [&](size_t bytes) -> void* {
    void* p = ws + off;
    off += (bytes + 255) & ~(size_t)255;
    return p;
  };
  float* qkvb = (float*)alloc(sizeof(float)*2*48*65536);   // reused as eig T-scratch after k2
  float* pq   = (float*)alloc(sizeof(float)*32*65536);
  float* pk   = (float*)alloc(sizeof(float)*32*65536);     // reused as Yt after k4
  float* pv   = (float*)alloc(sizeof(float)*32*65536);
  double* xc  = (double*)alloc(sizeof(double)*32*65536);   // later reused as A
  double* cov = (double*)alloc(sizeof(double)*32*65536);
  double* V   = (double*)alloc(sizeof(double)*32*65536);
  double* q2  = (double*)alloc(sizeof(double)*32*65536);
  double* sbuf= (double*)alloc(sizeof(double)*32*65536);
  double* Y   = (double*)alloc(sizeof(double)*32*256*128);
  float* out1 = (float*)alloc(sizeof(float)*32*65536);
  double* f64a= (double*)alloc(sizeof(double)*32*4096);
  int* i32a   = (int*)alloc(sizeof(int)*32*4096);
  if (off > ws_size) return;

  double* Tg = (double*)qkvb;   // qkvb dead after k2; fully rewritten by k1 each call
  double* Yt = (double*)pk;     // pk dead after k4; 8,388,608B == 32*128*256*8 exactly

  // Recreate call-1's initial conditions every call: zero the eig scratch.
  hipMemsetAsync(q2,   0, sizeof(double)*32*65536, stream);
  hipMemsetAsync(sbuf, 0, sizeof(double)*32*65536, stream);
  hipMemsetAsync(f64a, 0, sizeof(double)*32*4096,  stream);
  hipMemsetAsync(i32a, 0, sizeof(int)*32*4096,     stream);

  hipFuncSetAttribute((const void*)eig_bt, hipFuncAttributeMaxDynamicSharedMemorySize, 64*257*8);

  dim3 blk(256);
  k1_qkv<<<(2*48*65536 + 255)/256, blk, 0, stream>>>(x, w_qkv, qkvb);
  k2_dw_patch<<<(2*48*65536 + 255)/256, blk, 0, stream>>>(qkvb, w_dw, pq, pk, pv);
  k3_norms<<<32, blk, 0, stream>>>(pq, pk, f64a);
  k4_attn<<<8192, blk, 0, stream>>>(pq, pk, temperature, f64a, xc);
  k5_cov<<<8192, blk, 0, stream>>>(xc, cov);
  k5b_trace<<<32, blk, 0, stream>>>(cov, f64a);
  k5c_scale<<<8192, blk, 0, stream>>>(cov, f64a);

  eig_tridiag<<<32, 1024, 0, stream>>>(cov, V, f64a);
  eig_leaves<<<512, 64, 0, stream>>>(V, f64a, i32a);
  eig_merge<<<32*8, blk, 0, stream>>>(V, q2, sbuf, Tg, f64a, i32a, 32, 8);
  eig_merge<<<32*4, blk, 0, stream>>>(V, q2, sbuf, Tg, f64a, i32a, 64, 4);
  eig_merge<<<32*2, blk, 0, stream>>>(V, q2, sbuf, Tg, f64a, i32a, 128, 2);
  eig_merge<<<32*1, blk, 0, stream>>>(V, q2, sbuf, Tg, f64a, i32a, 256, 1);
  eig_perm<<<32, blk, 0, stream>>>(V, sbuf, f64a, i32a);
  eig_bt<<<128, 64, 64*257*8, stream>>>(cov, sbuf, V, f64a);

  k7_y<<<8192, blk, 0, stream>>>(V, w_fr, Y, Yt);
  k8_a<<<8192, blk, 0, stream>>>(Y, Yt, xc);
  k9_av<<<8192, blk, 0, stream>>>(xc, pv, out1);
  k10_final<<<(2*16*65536 + 255)/256, blk, 0, stream>>>(out1, w_po, out);
  (void)in_sizes; (void)n_in; (void)out_size;
}

// Round 12
// 8813.389 us; speedup vs baseline: 1.0989x; 1.0989x over previous
//
#include <hip/hip_runtime.h>
#include <math.h>

#define NEIG 256
#define LDQ 256
#define SMLSIZ 25
#define EPSD 1.1102230246251565e-16
#define SAFMND 2.2250738585072014e-308

// ======================= scalar LAPACK helpers =======================
__device__ __forceinline__ double fsign(double a, double b){ return copysign(a, b); }

__device__ __forceinline__ double dlapy2(double x, double y){
  double xa = fabs(x), ya = fabs(y);
  double w = fmax(xa, ya), z = fmin(xa, ya);
  if (z == 0.0) return w;
  double t = z / w;
  return w * sqrt(1.0 + t*t);
}

// LAPACK >= 3.10 dlartg (numpy's OpenBLAS): c >= 0 always.
__device__ void dlartg(double f, double g, double& c, double& s, double& r){
  const double safmin = SAFMND;
  const double safmax = 1.0/SAFMND;
  double f1 = fabs(f), g1 = fabs(g);
  if (g == 0.0){ c = 1.0; s = 0.0; r = f; }
  else if (f == 0.0){ c = 0.0; s = copysign(1.0, g); r = g1; }
  else {
    double rtmin = sqrt(safmin);
    double rtmax = sqrt(safmax/2.0);
    if (f1 > rtmin && f1 < rtmax && g1 > rtmin && g1 < rtmax){
      double d = sqrt(f*f + g*g);
      c = f1/d;
      r = copysign(d, f);
      s = g/r;
    } else {
      double u = fmin(safmax, fmax(safmin, fmax(f1, g1)));
      double fs = f/u, gs = g/u;
      double d = sqrt(fs*fs + gs*gs);
      c = fabs(fs)/d;
      r = copysign(d, f);
      s = gs/r;
      r = r*u;
    }
  }
}

__device__ void dlaev2(double a, double b, double c, double& rt1, double& rt2, double& cs1, double& sn1){
  double sm = a + c, df = a - c, adf = fabs(df), tb = b + b, ab = fabs(tb);
  double acmx, acmn;
  if (fabs(a) > fabs(c)){ acmx = a; acmn = c; } else { acmx = c; acmn = a; }
  double rt;
  if (adf > ab) rt = adf*sqrt(1.0 + (ab/adf)*(ab/adf));
  else if (adf < ab) rt = ab*sqrt(1.0 + (adf/ab)*(adf/ab));
  else rt = ab*sqrt(2.0);
  int sgn1;
  if (sm < 0.0){ rt1 = 0.5*(sm - rt); sgn1 = -1; rt2 = (acmx/rt1)*acmn - (b/rt1)*b; }
  else if (sm > 0.0){ rt1 = 0.5*(sm + rt); sgn1 = 1; rt2 = (acmx/rt1)*acmn - (b/rt1)*b; }
  else { rt1 = 0.5*rt; rt2 = -0.5*rt; sgn1 = 1; }
  double cs; int sgn2;
  if (df >= 0.0){ cs = df + rt; sgn2 = 1; } else { cs = df - rt; sgn2 = -1; }
  double acs = fabs(cs);
  if (acs > ab){ double ct = -tb/cs; sn1 = 1.0/sqrt(1.0 + ct*ct); cs1 = ct*sn1; }
  else {
    if (ab == 0.0){ cs1 = 1.0; sn1 = 0.0; }
    else { double tn = -cs/tb; cs1 = 1.0/sqrt(1.0 + tn*tn); sn1 = tn*cs1; }
  }
  if (sgn1 == sgn2){ double tn = cs1; cs1 = -sn1; sn1 = tn; }
}

__device__ void dlamrg(int n1, int n2, const double* a, int dtrd1, int dtrd2, int* index){
  int n1sv = n1, n2sv = n2, ind1, ind2;
  if (dtrd1 > 0) ind1 = 1; else ind1 = n1;
  if (dtrd2 > 0) ind2 = 1 + n1; else ind2 = n1 + n2;
  int i = 1;
  while (n1sv > 0 && n2sv > 0){
    if (a[ind1] <= a[ind2]){ index[i++] = ind1; ind1 += dtrd1; n1sv--; }
    else { index[i++] = ind2; ind2 += dtrd2; n2sv--; }
  }
  if (n1sv == 0){ while (n2sv > 0){ index[i++] = ind2; ind2 += dtrd2; n2sv--; } }
  else { while (n1sv > 0){ index[i++] = ind1; ind1 += dtrd1; n1sv--; } }
}

// ======================= dsteqr (serial, compz='I') =======================
__device__ void dsteqr_serial(int n, double* d, double* e, double* zb, int ldz, double* work){
#define ZZL(i,j) zb[((i)-1) + (size_t)((j)-1)*ldz]
  const double eps = EPSD, eps2 = EPSD*EPSD, safmin = SAFMND;
  const double ssfmax = sqrt(1.0/SAFMND)/3.0;
  const double ssfmin = sqrt(SAFMND)/(EPSD*EPSD);
  if (n <= 0) return;
  if (n == 1){ ZZL(1,1) = 1.0; return; }
  for (int j = 1; j <= n; j++)
    for (int i = 1; i <= n; i++)
      ZZL(i,j) = (i == j) ? 1.0 : 0.0;
  int nmaxit = n*30, jtot = 0;
  int l1 = 1, nm1 = n - 1;
  while (true){
    if (l1 > n) break;
    if (l1 > 1) e[l1-1] = 0.0;
    int m = n;
    if (l1 <= nm1){
      for (int mm = l1; mm <= nm1; mm++){
        double tst = fabs(e[mm]);
        if (tst == 0.0){ m = mm; break; }
        if (tst <= (sqrt(fabs(d[mm]))*sqrt(fabs(d[mm+1])))*eps){ e[mm] = 0.0; m = mm; break; }
      }
    }
    int l = l1, lsv = l, lend = m, lendsv = lend;
    l1 = m + 1;
    if (lend == l) continue;
    double anorm = 0.0;
    for (int i = l; i <= lend; i++) anorm = fmax(anorm, fabs(d[i]));
    for (int i = l; i <= lend-1; i++) anorm = fmax(anorm, fabs(e[i]));
    int iscale = 0;
    if (anorm == 0.0) continue;
    if (anorm > ssfmax){
      iscale = 1; double f = ssfmax/anorm;
      for (int i = l; i <= lend; i++) d[i] *= f;
      for (int i = l; i <= lend-1; i++) e[i] *= f;
    } else if (anorm < ssfmin){
      iscale = 2; double f = ssfmin/anorm;
      for (int i = l; i <= lend; i++) d[i] *= f;
      for (int i = l; i <= lend-1; i++) e[i] *= f;
    }
    if (fabs(d[lend]) < fabs(d[l])){ lend = lsv; l = lendsv; }
    if (lend > l){
      while (true){
        int mm = lend;
        if (l != lend){
          for (int m2 = l; m2 <= lend-1; m2++){
            double tst = e[m2]*e[m2];
            if (tst <= (eps2*fabs(d[m2]))*fabs(d[m2+1]) + safmin){ mm = m2; break; }
          }
        }
        if (mm < lend) e[mm] = 0.0;
        double p = d[l];
        if (mm == l){
          d[l] = p; l++;
          if (l <= lend) continue;
          break;
        }
        if (mm == l+1){
          double rt1, rt2, c, s;
          dlaev2(d[l], e[l], d[l+1], rt1, rt2, c, s);
          work[l] = c; work[n-1+l] = s;
          for (int i = 1; i <= n; i++){
            double t2 = ZZL(i, l+1);
            ZZL(i, l+1) = c*t2 - s*ZZL(i, l);
            ZZL(i, l)   = s*t2 + c*ZZL(i, l);
          }
          d[l] = rt1; d[l+1] = rt2; e[l] = 0.0;
          l += 2;
          if (l <= lend) continue;
          break;
        }
        if (jtot == nmaxit) break;
        jtot++;
        double g = (d[l+1]-p)/(2.0*e[l]);
        double r = dlapy2(g, 1.0);
        g = d[mm] - p + (e[l]/(g + fsign(r, g)));
        double s = 1.0, c = 1.0;
        p = 0.0;
        for (int i = mm-1; i >= l; i--){
          double f = s*e[i], b = c*e[i];
          dlartg(g, f, c, s, r);
          if (i != mm-1) e[i+1] = r;
          g = d[i+1] - p;
          r = (d[i]-g)*s + 2.0*c*b;
          p = s*r;
          d[i+1] = g + p;
          g = c*r - b;
          work[i] = c; work[n-1+i] = -s;
        }
        {
          int cnt = mm - l + 1;
          for (int jj = cnt-1; jj >= 1; jj--){
            double ct = work[l+jj-1], st = work[n-1+l+jj-1];
            for (int i = 1; i <= n; i++){
              double t2 = ZZL(i, l+jj);
              ZZL(i, l+jj)   = ct*t2 - st*ZZL(i, l+jj-1);
              ZZL(i, l+jj-1) = st*t2 + ct*ZZL(i, l+jj-1);
            }
          }
        }
        d[l] -= p;
        e[l] = g;
      }
    } else {
      while (true){
        int mm = lend;
        if (l != lend){
          for (int m2 = l; m2 >= lend+1; m2--){
            double tst = e[m2-1]*e[m2-1];
            if (tst <= (eps2*fabs(d[m2]))*fabs(d[m2-1]) + safmin){ mm = m2; break; }
          }
        }
        if (mm > lend) e[mm-1] = 0.0;
        double p = d[l];
        if (mm == l){
          d[l] = p; l--;
          if (l >= lend) continue;
          break;
        }
        if (mm == l-1){
          double rt1, rt2, c, s;
          dlaev2(d[l-1], e[l-1], d[l], rt1, rt2, c, s);
          work[mm] = c; work[n-1+mm] = s;
          for (int i = 1; i <= n; i++){
            double t2 = ZZL(i, l);
            ZZL(i, l)   = c*t2 - s*ZZL(i, l-1);
            ZZL(i, l-1) = s*t2 + c*ZZL(i, l-1);
          }
          d[l-1] = rt1; d[l] = rt2; e[l-1] = 0.0;
          l -= 2;
          if (l >= lend) continue;
          break;
        }
        if (jtot == nmaxit) break;
        jtot++;
        double g = (d[l-1]-p)/(2.0*e[l-1]);
        double r = dlapy2(g, 1.0);
        g = d[mm] - p + (e[l-1]/(g + fsign(r, g)));
        double s = 1.0, c = 1.0;
        p = 0.0;
        for (int i = mm; i <= l-1; i++){
          double f = s*e[i], b = c*e[i];
          dlartg(g, f, c, s, r);
          if (i != mm) e[i-1] = r;
          g = d[i] - p;
          r = (d[i+1]-g)*s + 2.0*c*b;
          p = s*r;
          d[i] = g + p;
          g = c*r - b;
          work[i] = c; work[n-1+i] = s;
        }
        {
          int cnt = l - mm + 1;
          for (int jj = 1; jj <= cnt-1; jj++){
            double ct = work[mm+jj-1], st = work[n-1+mm+jj-1];
            for (int i = 1; i <= n; i++){
              double t2 = ZZL(i, mm+jj);
              ZZL(i, mm+jj)   = ct*t2 - st*ZZL(i, mm+jj-1);
              ZZL(i, mm+jj-1) = st*t2 + ct*ZZL(i, mm+jj-1);
            }
          }
        }
        d[l] -= p;
        e[l-1] = g;
      }
    }
    if (iscale == 1){
      double f = anorm/ssfmax;
      for (int i = lsv; i <= lendsv; i++) d[i] *= f;
      for (int i = lsv; i <= lendsv-1; i++) e[i] *= f;
    } else if (iscale == 2){
      double f = anorm/ssfmin;
      for (int i = lsv; i <= lendsv; i++) d[i] *= f;
      for (int i = lsv; i <= lendsv-1; i++) e[i] *= f;
    }
  }
  for (int ii = 2; ii <= n; ii++){
    int i = ii - 1, kk = i;
    double p = d[i];
    for (int j = ii; j <= n; j++){ if (d[j] < p){ kk = j; p = d[j]; } }
    if (kk != i){
      d[kk] = d[i]; d[i] = p;
      for (int r = 1; r <= n; r++){ double t2 = ZZL(r,i); ZZL(r,i) = ZZL(r,kk); ZZL(r,kk) = t2; }
    }
  }
#undef ZZL
}

// ======================= dlaed5 (strided delta) =======================
__device__ void dlaed5(int i, const double* d, const double* z, double* delta, int dst,
                       double rho, double& dlam){
#define DL5(j) delta[(size_t)((j)-1)*dst]
  double del = d[2] - d[1];
  if (i == 1){
    double w = 1.0 + 2.0*rho*(z[2]*z[2] - z[1]*z[1])/del;
    if (w > 0.0){
      double b = del + rho*(z[1]*z[1] + z[2]*z[2]);
      double c = rho*z[1]*z[1]*del;
      double tau = 2.0*c/(b + sqrt(fabs(b*b - 4.0*c)));
      dlam = d[1] + tau;
      DL5(1) = -z[1]/tau;
      DL5(2) = z[2]/(del - tau);
    } else {
      double b = -del + rho*(z[1]*z[1] + z[2]*z[2]);
      double c = rho*z[2]*z[2]*del;
      double tau;
      if (b > 0.0) tau = -2.0*c/(b + sqrt(b*b + 4.0*c));
      else tau = (b - sqrt(b*b + 4.0*c))/2.0;
      dlam = d[2] + tau;
      DL5(1) = -z[1]/(del + tau);
      DL5(2) = -z[2]/tau;
    }
    double temp = sqrt(DL5(1)*DL5(1) + DL5(2)*DL5(2));
    DL5(1) /= temp; DL5(2) /= temp;
  } else {
    double b = -del + rho*(z[1]*z[1] + z[2]*z[2]);
    double c = rho*z[2]*z[2]*del;
    double tau;
    if (b > 0.0) tau = (b + sqrt(b*b + 4.0*c))/2.0;
    else tau = 2.0*c/(-b + sqrt(b*b + 4.0*c));
    dlam = d[2] + tau;
    DL5(1) = -z[1]/(del + tau);
    DL5(2) = -z[2]/tau;
    double temp = sqrt(DL5(1)*DL5(1) + DL5(2)*DL5(2));
    DL5(1) /= temp; DL5(2) /= temp;
  }
#undef DL5
}

// ======================= dlaed6 =======================
__device__ void dlaed6(int kniter, bool orgati, double rho, const double* dd, const double* zz,
                       double finit, double& tau, int& info){
  const int maxit = 40;
  info = 0;
  double lbd, ubd;
  if (orgati){ lbd = dd[2]; ubd = dd[3]; }
  else { lbd = dd[1]; ubd = dd[2]; }
  if (finit < 0.0) lbd = 0.0; else ubd = 0.0;
  tau = 0.0;
  if (kniter == 2){
    double temp, a, b, c;
    if (orgati){
      temp = (dd[3] + dd[2])/2.0;
      c = rho + zz[1]/(dd[1] - temp);
      a = c*(dd[2] + dd[3]) + zz[2] + zz[3];
      b = c*dd[2]*dd[3] + zz[2]*dd[3] + zz[3]*dd[2];
    } else {
      temp = (dd[1] + dd[2])/2.0;
      c = rho + zz[3]/(dd[3] - temp);
      a = c*(dd[1] + dd[2]) + zz[1] + zz[2];
      b = c*dd[1]*dd[2] + zz[1]*dd[2] + zz[2]*dd[1];
    }
    temp = fmax(fabs(a), fmax(fabs(b), fabs(c)));
    a /= temp; b /= temp; c /= temp;
    if (c == 0.0) tau = b/a;
    else if (a <= 0.0) tau = (a - sqrt(fabs(a*a - 4.0*b*c)))/(2.0*c);
    else tau = 2.0*b/(a + sqrt(fabs(a*a - 4.0*b*c)));
    if (tau < lbd || tau > ubd) tau = (lbd + ubd)/2.0;
    if (dd[1] == tau || dd[2] == tau || dd[3] == tau){
      tau = 0.0;
    } else {
      temp = finit + tau*zz[1]/(dd[1]*(dd[1]-tau))
                   + tau*zz[2]/(dd[2]*(dd[2]-tau))
                   + tau*zz[3]/(dd[3]*(dd[3]-tau));
      if (temp <= 0.0) lbd = tau; else ubd = tau;
      if (fabs(finit) <= fabs(temp)) tau = 0.0;
    }
  }
  const double small1 = 0x1p-340, sminv1 = 0x1p+340;
  const double small2 = small1*small1, sminv2 = sminv1*sminv1;
  double dscale[4], zscale[4];
  double temp2;
  if (orgati) temp2 = fmin(fabs(dd[2]-tau), fabs(dd[3]-tau));
  else temp2 = fmin(fabs(dd[1]-tau), fabs(dd[2]-tau));
  bool scalef = false;
  double sclinv = 1.0;
  if (temp2 <= small1){
    scalef = true;
    double sclfac;
    if (temp2 <= small2){ sclfac = sminv2; sclinv = small2; }
    else { sclfac = sminv1; sclinv = small1; }
    for (int i = 1; i <= 3; i++){ dscale[i] = dd[i]*sclfac; zscale[i] = zz[i]*sclfac; }
    tau *= sclfac; lbd *= sclfac; ubd *= sclfac;
  } else {
    for (int i = 1; i <= 3; i++){ dscale[i] = dd[i]; zscale[i] = zz[i]; }
  }
  double fc = 0.0, df = 0.0, ddf = 0.0;
  for (int i = 1; i <= 3; i++){
    double t = 1.0/(dscale[i] - tau);
    double t1 = zscale[i]*t;
    double t2 = t1*t;
    double t3 = t2*t;
    fc += t1/dscale[i];
    df += t2;
    ddf += t3;
  }
  double f = finit + tau*fc;
  if (fabs(f) > 0.0){
    if (f <= 0.0) lbd = tau; else ubd = tau;
    bool converged = false;
    for (int it = 2; it <= maxit; it++){
      double temp1v, temp2v;
      if (orgati){ temp1v = dscale[2] - tau; temp2v = dscale[3] - tau; }
      else { temp1v = dscale[1] - tau; temp2v = dscale[2] - tau; }
      double a = (temp1v + temp2v)*f - temp1v*temp2v*df;
      double b = temp1v*temp2v*f;
      double c = f - (temp1v + temp2v)*df + temp1v*temp2v*ddf;
      double temp = fmax(fabs(a), fmax(fabs(b), fabs(c)));
      a /= temp; b /= temp; c /= temp;
      double eta;
      if (c == 0.0) eta = b/a;
      else if (a <= 0.0) eta = (a - sqrt(fabs(a*a - 4.0*b*c)))/(2.0*c);
      else eta = 2.0*b/(a + sqrt(fabs(a*a - 4.0*b*c)));
      if (f*eta >= 0.0) eta = -f/df;
      tau += eta;
      if (tau < lbd || tau > ubd) tau = (lbd + ubd)/2.0;
      fc = 0.0; df = 0.0; ddf = 0.0;
      double erretm = 0.0;
      bool hitzero = false;
      for (int i = 1; i <= 3; i++){
        if ((dscale[i] - tau) != 0.0){
          double t = 1.0/(dscale[i] - tau);
          double t1 = zscale[i]*t;
          double t2 = t1*t;
          double t3 = t2*t;
          double t4 = t1/dscale[i];
          fc += t4;
          erretm += fabs(t4);
          df += t2;
          ddf += t3;
        } else { hitzero = true; break; }
      }
      if (hitzero){ converged = true; break; }
      f = finit + tau*fc;
      erretm = 8.0*(fabs(finit) + fabs(tau)*erretm) + fabs(tau)*df;
      if (fabs(f) <= EPSD*erretm){ converged = true; break; }
      if (f <= 0.0) lbd = tau; else ubd = tau;
    }
    if (!converged) info = 1;
  }
  if (scalef) tau *= sclinv;
}

// ======================= dlaed4 (strided delta) =======================
__device__ void dlaed4(int n, int i, const double* d, const double* z, double* delta, int dst,
                       double rho, double& dlam, int& info){
#define DL(j) delta[(size_t)((j)-1)*dst]
  const int maxit = 30;
  info = 0;
  if (n == 1){ dlam = d[1] + rho*z[1]*z[1]; DL(1) = 1.0; return; }
  if (n == 2){ dlaed5(i, d, z, delta, dst, rho, dlam); return; }
  const double eps = EPSD;
  double rhoinv = 1.0/rho;

  if (i == n){
    int ii = n - 1;
    double midpt = rho/2.0;
    for (int j = 1; j <= n; j++) DL(j) = (d[j] - d[i]) - midpt;
    double psi = 0.0;
    for (int j = 1; j <= n-2; j++) psi += z[j]*z[j]/DL(j);
    double c = rhoinv + psi;
    double w = c + z[ii]*z[ii]/DL(ii) + z[n]*z[n]/DL(n);
    double tau, dltlb, dltub;
    if (w <= 0.0){
      double temp = z[n-1]*z[n-1]/(d[n]-d[n-1]+rho) + z[n]*z[n]/rho;
      if (c <= temp) tau = rho;
      else {
        double del = d[n] - d[n-1];
        double a = -c*del + z[n-1]*z[n-1] + z[n]*z[n];
        double b = z[n]*z[n]*del;
        if (a < 0.0) tau = 2.0*b/(sqrt(a*a + 4.0*b*c) - a);
        else tau = (a + sqrt(a*a + 4.0*b*c))/(2.0*c);
      }
      dltlb = midpt; dltub = rho;
    } else {
      double del = d[n] - d[n-1];
      double a = -c*del + z[n-1]*z[n-1] + z[n]*z[n];
      double b = z[n]*z[n]*del;
      if (a < 0.0) tau = 2.0*b/(sqrt(a*a + 4.0*b*c) - a);
      else tau = (a + sqrt(a*a + 4.0*b*c))/(2.0*c);
      dltlb = 0.0; dltub = midpt;
    }
    for (int j = 1; j <= n; j++) DL(j) = (d[j] - d[i]) - tau;
    double dpsi = 0.0, erretm = 0.0; psi = 0.0;
    for (int j = 1; j <= ii; j++){
      double t2 = z[j]/DL(j);
      psi += z[j]*t2; dpsi += t2*t2; erretm += psi;
    }
    erretm = fabs(erretm);
    double temp = z[n]/DL(n);
    double phi = z[n]*temp, dphi = temp*temp;
    erretm = 8.0*(-phi - psi) + erretm - phi + rhoinv + fabs(tau)*(dpsi + dphi);
    w = rhoinv + phi + psi;
    if (fabs(w) <= eps*erretm){ dlam = d[i] + tau; return; }
    if (w <= 0.0) dltlb = fmax(dltlb, tau); else dltub = fmin(dltub, tau);
    c = w - DL(n-1)*dpsi - DL(n)*dphi;
    double a = (DL(n-1) + DL(n))*w - DL(n-1)*DL(n)*(dpsi + dphi);
    double b = DL(n-1)*DL(n)*w;
    if (c < 0.0) c = fabs(c);
    double eta;
    if (c == 0.0) eta = dltub - tau;
    else if (a >= 0.0) eta = (a + sqrt(fabs(a*a - 4.0*b*c)))/(2.0*c);
    else eta = 2.0*b/(a - sqrt(fabs(a*a - 4.0*b*c)));
    if (w*eta > 0.0) eta = -w/(dpsi + dphi);
    temp = tau + eta;
    if (temp > dltub || temp < dltlb){
      if (w < 0.0) eta = (dltub - tau)/2.0; else eta = (dltlb - tau)/2.0;
    }
    for (int j = 1; j <= n; j++) DL(j) -= eta;
    tau += eta;
    dpsi = 0.0; psi = 0.0; erretm = 0.0;
    for (int j = 1; j <= ii; j++){
      double t2 = z[j]/DL(j);
      psi += z[j]*t2; dpsi += t2*t2; erretm += psi;
    }
    erretm = fabs(erretm);
    temp = z[n]/DL(n);
    phi = z[n]*temp; dphi = temp*temp;
    erretm = 8.0*(-phi - psi) + erretm - phi + rhoinv + fabs(tau)*(dpsi + dphi);
    w = rhoinv + phi + psi;
    for (int it = 3; it <= maxit; it++){
      if (fabs(w) <= eps*erretm){ dlam = d[i] + tau; return; }
      if (w <= 0.0) dltlb = fmax(dltlb, tau); else dltub = fmin(dltub, tau);
      c = w - DL(n-1)*dpsi - DL(n)*dphi;
      a = (DL(n-1) + DL(n))*w - DL(n-1)*DL(n)*(dpsi + dphi);
      b = DL(n-1)*DL(n)*w;
      if (a >= 0.0) eta = (a + sqrt(fabs(a*a - 4.0*b*c)))/(2.0*c);
      else eta = 2.0*b/(a - sqrt(fabs(a*a - 4.0*b*c)));
      if (w*eta > 0.0) eta = -w/(dpsi + dphi);
      temp = tau + eta;
      if (temp > dltub || temp < dltlb){
        if (w < 0.0) eta = (dltub - tau)/2.0; else eta = (dltlb - tau)/2.0;
      }
      for (int j = 1; j <= n; j++) DL(j) -= eta;
      tau += eta;
      dpsi = 0.0; psi = 0.0; erretm = 0.0;
      for (int j = 1; j <= ii; j++){
        double t2 = z[j]/DL(j);
        psi += z[j]*t2; dpsi += t2*t2; erretm += psi;
      }
      erretm = fabs(erretm);
      temp = z[n]/DL(n);
      phi = z[n]*temp; dphi = temp*temp;
      erretm = 8.0*(-phi - psi) + erretm - phi + rhoinv + fabs(tau)*(dpsi + dphi);
      w = rhoinv + phi + psi;
    }
    info = 1; dlam = d[i] + tau; return;
  }

  {
    int ip1 = i + 1;
    double del = d[ip1] - d[i];
    double midpt = del/2.0;
    for (int j = 1; j <= n; j++) DL(j) = (d[j] - d[i]) - midpt;
    double psi = 0.0;
    for (int j = 1; j <= i-1; j++) psi += z[j]*z[j]/DL(j);
    double phi = 0.0;
    for (int j = n; j >= i+2; j--) phi += z[j]*z[j]/DL(j);
    double c = rhoinv + psi + phi;
    double w = c + z[i]*z[i]/DL(i) + z[ip1]*z[ip1]/DL(ip1);
    bool orgati;
    double tau, dltlb, dltub;
    if (w > 0.0){
      orgati = true;
      double a = c*del + z[i]*z[i] + z[ip1]*z[ip1];
      double b = z[i]*z[i]*del;
      if (a > 0.0) tau = 2.0*b/(a + sqrt(fabs(a*a - 4.0*b*c)));
      else tau = (a - sqrt(fabs(a*a - 4.0*b*c)))/(2.0*c);
      dltlb = 0.0; dltub = midpt;
    } else {
      orgati = false;
      double a = c*del - z[i]*z[i] - z[ip1]*z[ip1];
      double b = z[ip1]*z[ip1]*del;
      if (a < 0.0) tau = 2.0*b/(a - sqrt(fabs(a*a + 4.0*b*c)));
      else tau = -(a + sqrt(fabs(a*a + 4.0*b*c)))/(2.0*c);
      dltlb = -midpt; dltub = 0.0;
    }
    if (orgati){ for (int j = 1; j <= n; j++) DL(j) = (d[j] - d[i]) - tau; }
    else { for (int j = 1; j <= n; j++) DL(j) = (d[j] - d[ip1]) - tau; }
    int ii = orgati ? i : i+1;
    int iim1 = ii - 1, iip1 = ii + 1;
    double dpsi = 0.0, erretm = 0.0; psi = 0.0;
    for (int j = 1; j <= iim1; j++){
      double t2 = z[j]/DL(j);
      psi += z[j]*t2; dpsi += t2*t2; erretm += psi;
    }
    erretm = fabs(erretm);
    double dphi = 0.0; phi = 0.0;
    for (int j = n; j >= iip1; j--){
      double t2 = z[j]/DL(j);
      phi += z[j]*t2; dphi += t2*t2; erretm += phi;
    }
    w = rhoinv + phi + psi;
    bool swtch3 = false;
    if (orgati){ if (w < 0.0) swtch3 = true; }
    else { if (w > 0.0) swtch3 = true; }
    if (ii == 1 || ii == n) swtch3 = false;
    double temp = z[ii]/DL(ii);
    double dw = dpsi + dphi + temp*temp;
    temp = z[ii]*temp;
    w += temp;
    erretm = 8.0*(phi - psi) + erretm + 2.0*rhoinv + 3.0*fabs(temp) + fabs(tau)*dw;
    if (fabs(w) <= eps*erretm){ dlam = (orgati ? d[i] : d[ip1]) + tau; return; }
    if (w <= 0.0) dltlb = fmax(dltlb, tau); else dltub = fmin(dltub, tau);
    double eta;
    double zz[4];
    if (!swtch3){
      double cc;
      if (orgati) cc = w - DL(ip1)*dw - (d[i]-d[ip1])*(z[i]/DL(i))*(z[i]/DL(i));
      else cc = w - DL(i)*dw - (d[ip1]-d[i])*(z[ip1]/DL(ip1))*(z[ip1]/DL(ip1));
      double a = (DL(i) + DL(ip1))*w - DL(i)*DL(ip1)*dw;
      double b = DL(i)*DL(ip1)*w;
      if (cc == 0.0){
        if (a == 0.0){
          if (orgati) a = z[i]*z[i] + DL(ip1)*DL(ip1)*(dpsi + dphi);
          else a = z[ip1]*z[ip1] + DL(i)*DL(i)*(dpsi + dphi);
        }
        eta = b/a;
      } else if (a <= 0.0) eta = (a - sqrt(fabs(a*a - 4.0*b*cc)))/(2.0*cc);
      else eta = 2.0*b/(a + sqrt(fabs(a*a - 4.0*b*cc)));
    } else {
      double tempc = rhoinv + psi + phi;
      double cc;
      if (orgati){
        double temp1 = z[iim1]/DL(iim1);
        temp1 = temp1*temp1;
        cc = tempc - DL(iip1)*(dpsi + dphi) - (d[iim1]-d[iip1])*temp1;
        zz[1] = z[iim1]*z[iim1];
        zz[3] = DL(iip1)*DL(iip1)*((dpsi - temp1) + dphi);
      } else {
        double temp1 = z[iip1]/DL(iip1);
        temp1 = temp1*temp1;
        cc = tempc - DL(iim1)*(dpsi + dphi) - (d[iip1]-d[iim1])*temp1;
        zz[1] = DL(iim1)*DL(iim1)*(dpsi + (dphi - temp1));
        zz[3] = z[iip1]*z[iip1];
      }
      zz[2] = z[ii]*z[ii];
      double dd3[4];
      dd3[1] = DL(iim1); dd3[2] = DL(ii); dd3[3] = DL(iip1);
      int info6;
      dlaed6(2, orgati, cc, dd3, zz, w, eta, info6);
      if (info6 != 0){ info = 1; dlam = (orgati ? d[i] : d[ip1]) + tau; return; }
    }
    if (w*eta >= 0.0) eta = -w/dw;
    temp = tau + eta;
    if (temp > dltub || temp < dltlb){
      if (w < 0.0) eta = (dltub - tau)/2.0; else eta = (dltlb - tau)/2.0;
    }
    double prew = w;
    for (int j = 1; j <= n; j++) DL(j) -= eta;
    tau += eta;
    dpsi = 0.0; psi = 0.0; erretm = 0.0;
    for (int j = 1; j <= iim1; j++){
      double t2 = z[j]/DL(j);
      psi += z[j]*t2; dpsi += t2*t2; erretm += psi;
    }
    erretm = fabs(erretm);
    dphi = 0.0; phi = 0.0;
    for (int j = n; j >= iip1; j--){
      double t2 = z[j]/DL(j);
      phi += z[j]*t2; dphi += t2*t2; erretm += phi;
    }
    temp = z[ii]/DL(ii);
    dw = dpsi + dphi + temp*temp;
    temp = z[ii]*temp;
    w = rhoinv + phi + psi + temp;
    erretm = 8.0*(phi - psi) + erretm + 2.0*rhoinv + 3.0*fabs(temp) + fabs(tau)*dw;
    bool swtch = false;
    if (orgati){ if (-w > fabs(prew)/10.0) swtch = true; }
    else { if (w > fabs(prew)/10.0) swtch = true; }
    for (int it = 3; it <= maxit; it++){
      if (fabs(w) <= eps*erretm){ dlam = (orgati ? d[i] : d[ip1]) + tau; return; }
      if (w <= 0.0) dltlb = fmax(dltlb, tau); else dltub = fmin(dltub, tau);
      if (!swtch3){
        double cc;
        if (!swtch){
          if (orgati) cc = w - DL(ip1)*dw - (d[i]-d[ip1])*(z[i]/DL(i))*(z[i]/DL(i));
          else cc = w - DL(i)*dw - (d[ip1]-d[i])*(z[ip1]/DL(ip1))*(z[ip1]/DL(ip1));
        } else {
          double t2 = z[ii]/DL(ii);
          if (orgati) dpsi += t2*t2;
          else dphi += t2*t2;
          cc = w - DL(i)*dpsi - DL(ip1)*dphi;
        }
        double a = (DL(i) + DL(ip1))*w - DL(i)*DL(ip1)*dw;
        double b = DL(i)*DL(ip1)*w;
        if (cc == 0.0){
          if (a == 0.0){
            if (!swtch){
              if (orgati) a = z[i]*z[i] + DL(ip1)*DL(ip1)*(dpsi + dphi);
              else a = z[ip1]*z[ip1] + DL(i)*DL(i)*(dpsi + dphi);
            } else {
              a = DL(i)*DL(i)*dpsi + DL(ip1)*DL(ip1)*dphi;
            }
          }
          eta = b/a;
        } else if (a <= 0.0) eta = (a - sqrt(fabs(a*a - 4.0*b*cc)))/(2.0*cc);
        else eta = 2.0*b/(a + sqrt(fabs(a*a - 4.0*b*cc)));
      } else {
        double tempc = rhoinv + psi + phi;
        double cc;
        if (swtch){
          cc = tempc - DL(iim1)*dpsi - DL(iip1)*dphi;
          zz[1] = DL(iim1)*DL(iim1)*dpsi;
          zz[3] = DL(iip1)*DL(iip1)*dphi;
        } else {
          if (orgati){
            double temp1 = z[iim1]/DL(iim1);
            temp1 = temp1*temp1;
            cc = tempc - DL(iip1)*(dpsi + dphi) - (d[iim1]-d[iip1])*temp1;
            zz[1] = z[iim1]*z[iim1];
            zz[3] = DL(iip1)*DL(iip1)*((dpsi - temp1) + dphi);
          } else {
            double temp1 = z[iip1]/DL(iip1);
            temp1 = temp1*temp1;
            cc = tempc - DL(iim1)*(dpsi + dphi) - (d[iip1]-d[iim1])*temp1;
            zz[1] = DL(iim1)*DL(iim1)*(dpsi + (dphi - temp1));
            zz[3] = z[iip1]*z[iip1];
          }
          zz[2] = z[ii]*z[ii];
        }
        double dd3[4];
        dd3[1] = DL(iim1); dd3[2] = DL(ii); dd3[3] = DL(iip1);
        int info6;
        dlaed6(it, orgati, cc, dd3, zz, w, eta, info6);
        if (info6 != 0){ info = 1; dlam = (orgati ? d[i] : d[ip1]) + tau; return; }
      }
      if (w*eta >= 0.0) eta = -w/dw;
      temp = tau + eta;
      if (temp > dltub || temp < dltlb){
        if (w < 0.0) eta = (dltub - tau)/2.0; else eta = (dltlb - tau)/2.0;
      }
      for (int j = 1; j <= n; j++) DL(j) -= eta;
      tau += eta;
      prew = w;
      dpsi = 0.0; psi = 0.0; erretm = 0.0;
      for (int j = 1; j <= iim1; j++){
        double t2 = z[j]/DL(j);
        psi += z[j]*t2; dpsi += t2*t2; erretm += psi;
      }
      erretm = fabs(erretm);
      dphi = 0.0; phi = 0.0;
      for (int j = n; j >= iip1; j--){
        double t2 = z[j]/DL(j);
        phi += z[j]*t2; dphi += t2*t2; erretm += phi;
      }
      temp = z[ii]/DL(ii);
      dw = dpsi + dphi + temp*temp;
      temp = z[ii]*temp;
      w = rhoinv + phi + psi + temp;
      erretm = 8.0*(phi - psi) + erretm + 2.0*rhoinv + 3.0*fabs(temp) + fabs(tau)*dw;
      if (w*prew > 0.0 && fabs(w) > fabs(prew)/10.0) swtch = !swtch;
    }
    info = 1; dlam = (orgati ? d[i] : d[ip1]) + tau; return;
  }
#undef DL
}

// ======================= dlaed2 scan (scalar only; records rotations) =======================
__device__ void dlaed2_scan(int& kOut, int n, int n1, double* d, int* indxq, double& rho,
    double* z, double* dlamda, double* w,
    int* indx, int* indxc, int* indxp, int* coltyp,
    int* rotp, int* rotn, double* rotc, double* rots, int& nrot,
    int* ctot, int& deflall){
  nrot = 0; deflall = 0;
  int n2 = n - n1, n1p1 = n1 + 1;
  if (rho < 0.0){ for (int j = n1p1; j <= n; j++) z[j] = -z[j]; }
  double tscal = 1.0/sqrt(2.0);
  for (int j = 1; j <= n; j++) z[j] *= tscal;
  rho = fabs(2.0*rho);
  for (int i = n1p1; i <= n; i++) indxq[i] += n1;
  for (int i = 1; i <= n; i++) dlamda[i] = d[indxq[i]];
  dlamrg(n1, n2, dlamda, 1, 1, indxc);
  for (int i = 1; i <= n; i++) indx[i] = indxq[indxc[i]];
  int imax = 1, jmax = 1;
  for (int j = 2; j <= n; j++) if (fabs(z[j]) > fabs(z[imax])) imax = j;
  for (int j = 2; j <= n; j++) if (fabs(d[j]) > fabs(d[jmax])) jmax = j;
  double tol = 8.0*EPSD*fmax(fabs(d[jmax]), fabs(z[imax]));
  if (rho*fabs(z[imax]) <= tol){
    kOut = 0; deflall = 1;
    for (int j = 1; j <= n; j++) dlamda[j] = d[indx[j]];
    ctot[1] = ctot[2] = ctot[3] = ctot[4] = 0;
    return;
  }
  for (int i = 1; i <= n1; i++) coltyp[i] = 1;
  for (int i = n1p1; i <= n; i++) coltyp[i] = 3;
  int k = 0, k2 = n + 1;
  int pj = 0, nj = 0, j = 0;
  bool allDone = false;
  for (j = 1; j <= n; j++){
    nj = indx[j];
    if (rho*fabs(z[nj]) <= tol){
      k2--; coltyp[nj] = 4; indxp[k2] = nj;
      if (j == n) allDone = true;
    } else { pj = nj; break; }
  }
  if (!allDone){
    while (true){
      j++;
      if (j > n) break;
      nj = indx[j];
      if (rho*fabs(z[nj]) <= tol){
        k2--; coltyp[nj] = 4; indxp[k2] = nj;
      } else {
        double sN = z[pj], cN = z[nj];
        double tau2 = dlapy2(cN, sN);
        double tdif = d[nj] - d[pj];
        cN = cN/tau2; sN = -sN/tau2;
        if (fabs(tdif*cN*sN) <= tol){
          z[nj] = tau2; z[pj] = 0.0;
          if (coltyp[nj] != coltyp[pj]) coltyp[nj] = 2;
          coltyp[pj] = 4;
          nrot++;
          rotp[nrot] = pj; rotn[nrot] = nj; rotc[nrot] = cN; rots[nrot] = sN;
          double tq = d[pj]*cN*cN + d[nj]*sN*sN;
          d[nj] = d[pj]*sN*sN + d[nj]*cN*cN;
          d[pj] = tq;
          k2--;
          int i2 = 1;
          while (true){
            if (k2 + i2 <= n){
              if (d[pj] < d[indxp[k2+i2]]){
                indxp[k2+i2-1] = indxp[k2+i2];
                indxp[k2+i2] = pj;
                i2++;
              } else { indxp[k2+i2-1] = pj; break; }
            } else { indxp[k2+i2-1] = pj; break; }
          }
          pj = nj;
        } else {
          k++; dlamda[k] = d[pj]; w[k] = z[pj]; indxp[k] = pj;
          pj = nj;
        }
      }
    }
    k++; dlamda[k] = d[pj]; w[k] = z[pj]; indxp[k] = pj;
  }
  int ct[5] = {0,0,0,0,0};
  for (int jj = 1; jj <= n; jj++) ct[coltyp[jj]]++;
  int psm[5];
  psm[1] = 1; psm[2] = 1 + ct[1]; psm[3] = psm[2] + ct[2]; psm[4] = psm[3] + ct[3];
  k = n - ct[4];
  for (int jj = 1; jj <= n; jj++){
    int js = indxp[jj];
    int cti = coltyp[js];
    indx[psm[cti]] = js;
    indxc[psm[cti]] = jj;
    psm[cti]++;
  }
  ctot[1] = ct[1]; ctot[2] = ct[2]; ctot[3] = ct[3]; ctot[4] = ct[4];
  kOut = k;
}

// ======================= eig stage 1: tridiagonalization (1024 thr) ===========
__global__ __launch_bounds__(1024) void eig_tridiag(
    double* __restrict__ covg, double* __restrict__ Vg,
    double* __restrict__ f64g){
  const int mtx = blockIdx.x;
  const int tid = threadIdx.x;     // 0..1023
  const int rp = tid & 255;        // row slot
  const int cp = tid >> 8;         // column chunk 0..3
  const int wid = tid >> 6;        // wave 0..15
  const int lane = tid & 63;
  double* A0 = covg + (size_t)mtx*65536;
  double* Q0 = Vg + (size_t)mtx*65536;
  double* F  = f64g + (size_t)mtx*4096;
  double* d1 = F - 1;
  double* e1 = F + 256 - 1;
  double* tau1 = F + 512 - 1;

  __shared__ double shv[257], shw[257], shp[1024], shpart[16];
  __shared__ double sh_d[4];

  for (int idx = tid; idx < 65536; idx += 1024) Q0[idx] = 0.0;
  __syncthreads();

  for (int i1 = 1; i1 <= NEIG-1; i1++){
    const int nr = NEIG - i1;
    double part = 0.0;
    for (int rr = 1+tid; rr <= nr; rr += 1024){
      double v = A0[(i1+rr-1) + (size_t)(i1-1)*LDQ];
      shv[rr] = v;
      if (rr >= 2) part += v*v;
    }
    for (int o = 32; o > 0; o >>= 1) part += __shfl_down(part, o);
    if (lane == 0) shpart[wid] = part;
    __syncthreads();
    if (tid == 0){
      double xn2 = 0.0;
      for (int w2 = 0; w2 < 16; w2++) xn2 += shpart[w2];
      double alpha = shv[1];
      double taui, scal = 0.0;
      if (xn2 == 0.0){ taui = 0.0; e1[i1] = alpha; }
      else {
        double xnorm = sqrt(xn2);
        double beta = -fsign(dlapy2(alpha, xnorm), alpha);
        taui = (beta - alpha)/beta;
        scal = 1.0/(alpha - beta);
        e1[i1] = beta;
      }
      tau1[i1] = taui;
      sh_d[0] = taui; sh_d[1] = scal;
    }
    __syncthreads();
    double taui = sh_d[0], scal = sh_d[1];
    if (taui != 0.0){
      for (int rr = 1+tid; rr <= nr; rr += 1024){
        if (rr == 1) shv[1] = 1.0;
        else {
          double nv = shv[rr]*scal;
          shv[rr] = nv;
          A0[(i1+rr-1) + (size_t)(i1-1)*LDQ] = nv;
        }
      }
      __syncthreads();
      int clen = (nr + 3) >> 2;
      int c0 = cp*clen + 1;
      int c1 = c0 + clen - 1; if (c1 > nr) c1 = nr;
      double pp = 0.0;
      if (rp + 1 <= nr){
        int r = i1 + rp + 1;
        const double* arow = A0 + (r-1);
        for (int cc = c0; cc <= c1; cc++)
          pp += arow[(size_t)(i1+cc-1)*LDQ]*shv[cc];
      }
      shp[cp*256 + rp] = pp;
      __syncthreads();
      double dotc = 0.0;
      if (tid < 256){
        if (tid + 1 <= nr){
          double acc = ((shp[tid] + shp[256+tid]) + (shp[512+tid] + shp[768+tid]))*taui;
          shw[tid+1] = acc;
          dotc = acc*shv[tid+1];
        }
        for (int o = 32; o > 0; o >>= 1) dotc += __shfl_down(dotc, o);
        if (lane == 0) shpart[wid] = dotc;
      }
      __syncthreads();
      if (tid < 256 && tid + 1 <= nr){
        double alpha2 = -0.5*taui*((shpart[0]+shpart[1])+(shpart[2]+shpart[3]));
        shw[tid+1] += alpha2*shv[tid+1];
      }
      __syncthreads();
      if (rp + 1 <= nr){
        int r = i1 + rp + 1;
        double vr = shv[rp+1], wr = shw[rp+1];
        double* arow = A0 + (r-1);
        for (int cc = c0; cc <= c1; cc++)
          arow[(size_t)(i1+cc-1)*LDQ] -= vr*shw[cc] + wr*shv[cc];
      }
      __syncthreads();
    }
  }
  for (int j = 1+tid; j <= NEIG; j += 1024) d1[j] = A0[(j-1) + (size_t)(j-1)*LDQ];
  __syncthreads();

  if (tid == 0){
    double mx = 0.0;
    for (int i = 1; i <= NEIG; i++) mx = fmax(mx, fabs(d1[i]));
    for (int i = 1; i <= NEIG-1; i++) mx = fmax(mx, fabs(e1[i]));
    F[3208] = mx;
    double mul = 1.0/mx;
    for (int i = 1; i <= NEIG; i++) d1[i] *= mul;
    for (int i = 1; i <= NEIG-1; i++) e1[i] *= mul;
    for (int i = 1; i <= 15; i++){
      int smm1 = 16*i;
      d1[smm1]   -= fabs(e1[smm1]);
      d1[smm1+1] -= fabs(e1[smm1]);
    }
  }
}

// ======================= eig stage 2: leaves (LDS dsteqr) =======================
__global__ __launch_bounds__(64) void eig_leaves(
    double* __restrict__ Vg, double* __restrict__ f64g, int* __restrict__ i32g){
  const int mtx = blockIdx.x >> 4;
  const int leaf = blockIdx.x & 15;
  const int tid = threadIdx.x;
  double* Q0 = Vg + (size_t)mtx*65536;
  double* F  = f64g + (size_t)mtx*4096;
  int* IA    = i32g + (size_t)mtx*4096;
  const int submat = leaf*16 + 1;  // 1-based

  __shared__ double shd[17], she[17], shwk[40], shZ[256];
  if (tid < 16) shd[tid+1] = F[submat-1 + tid];
  if (tid < 15) she[tid+1] = F[256 + submat-1 + tid];
  __syncthreads();
  if (tid == 0) dsteqr_serial(16, shd, she, shZ, 16, shwk);
  __syncthreads();
  for (int idx = tid; idx < 256; idx += 64){
    int c = idx >> 4, r = idx & 15;
    Q0[(submat-1+r) + (size_t)(submat-1+c)*LDQ] = shZ[r + c*16];
  }
  if (tid < 16){
    F[submat-1+tid] = shd[tid+1];
    IA[submat-1+tid] = tid+1;
  }
}

// ======================= eig stage 3: one D&C merge level =======================
__global__ __launch_bounds__(256) void eig_merge(
    double* __restrict__ Vg, double* __restrict__ q2g, double* __restrict__ sg,
    double* __restrict__ Tg,
    double* __restrict__ f64g, int* __restrict__ i32g, int n, int nmerges){
  const int bid = blockIdx.x;
  const int mtx = bid / nmerges;
  const int mi  = bid % nmerges;
  const int tid = threadIdx.x;
  double* Q0 = Vg + (size_t)mtx*65536;
  double* F  = f64g + (size_t)mtx*4096;
  int* IA    = i32g + (size_t)mtx*4096;
  double* d1 = F - 1;
  double* e1 = F + 256 - 1;
  int* indxqg = IA - 1;
  double* q2a = q2g + (size_t)mtx*65536 + (size_t)mi*n*n;
  double* sa  = sg  + (size_t)mtx*65536 + (size_t)mi*n*n;
  double* Ta  = Tg  + (size_t)mtx*65536 + (size_t)mi*n*n;
  const int s0 = mi*n + 1;
  const int cut = n/2;
#define QG(i,j) Q0[(s0-1 + (i)-1) + (size_t)(s0-1 + (j)-1)*LDQ]
#define TS(i,j) Ta[(size_t)((i)-1)*n + ((j)-1)]

  __shared__ double sd[257], sz[257], sdl[257], sw[257], sst[257], src_[257], srs_[257];
  __shared__ int siq[257], six[257], sic[257], sip[257], sit[257], srp_[257], srn_[257];
  __shared__ int sh_i[8];
  __shared__ double sh_d[2];

  for (int i = 1+tid; i <= n; i += 256){ sd[i] = d1[s0-1+i]; siq[i] = indxqg[s0-1+i]; }
  for (int j = 1+tid; j <= cut; j += 256) sz[j] = QG(cut, j);
  for (int j = cut+1+tid; j <= n; j += 256) sz[j] = QG(cut+1, j);
  __syncthreads();
  if (tid == 0){
    double rho = e1[s0 + cut - 1];
    int kk, nrot, defl;
    dlaed2_scan(kk, n, cut, sd, siq, rho, sz, sdl, sw, six, sic, sip, sit,
                srp_, srn_, src_, srs_, nrot, sh_i, defl);
    sh_i[0] = kk; sh_i[5] = nrot; sh_i[6] = defl; sh_d[0] = rho;
  }
  __syncthreads();
  const int k = sh_i[0];
  const int ct1 = sh_i[1], ct2 = sh_i[2], ct3 = sh_i[3], ct4 = sh_i[4];
  const int nrot = sh_i[5], defl = sh_i[6];
  const double rho = sh_d[0];
  const int nn1 = cut, nn2 = n - cut;

  if (defl){
    for (int idx = tid; idx < n*n; idx += 256){
      int j = idx / n, r = idx % n;
      q2a[idx] = QG(r+1, six[j+1]);
    }
    __syncthreads();
    for (int idx = tid; idx < n*n; idx += 256){
      int j = idx / n, r = idx % n;
      QG(r+1, j+1) = q2a[idx];
    }
    for (int i = 1+tid; i <= n; i += 256){
      d1[s0-1+i] = sdl[i];
      indxqg[s0-1+i] = i;
    }
    return;
  }

  {
    int r = tid + 1;
    if (r <= n){
      for (int t = 1; t <= nrot; t++){
        int pj = srp_[t], nj = srn_[t];
        double c = src_[t], s = srs_[t];
        double xq = QG(r, pj), yq = QG(r, nj);
        QG(r, pj) = c*xq + s*yq;
        QG(r, nj) = c*yq - s*xq;
      }
    }
  }
  __syncthreads();
  for (int i = 1+tid; i <= n; i += 256) sz[i] = sd[six[i]];
  __syncthreads();
  const int iq12 = ct1*nn1;
  const int iq2base = (ct1+ct2)*nn1;
  const int iq2b3 = iq2base + ct2*nn2;
  const int iq2d = iq2b3 + ct3*nn2;
  for (int idx = tid; idx < ct1*nn1; idx += 256){
    int jj = idx / nn1, r = idx % nn1;
    q2a[jj*nn1 + r] = QG(r+1, six[jj+1]);
  }
  for (int idx = tid; idx < ct2*nn1; idx += 256){
    int jj = idx / nn1, r = idx % nn1;
    q2a[iq12 + jj*nn1 + r] = QG(r+1, six[ct1+jj+1]);
  }
  for (int idx = tid; idx < ct2*nn2; idx += 256){
    int jj = idx / nn2, r = idx % nn2;
    q2a[iq2base + jj*nn2 + r] = QG(nn1+r+1, six[ct1+jj+1]);
  }
  for (int idx = tid; idx < ct3*nn2; idx += 256){
    int jj = idx / nn2, r = idx % nn2;
    q2a[iq2b3 + jj*nn2 + r] = QG(nn1+r+1, six[ct1+ct2+jj+1]);
  }
  for (int idx = tid; idx < ct4*n; idx += 256){
    int jj = idx / n, r = idx % n;
    q2a[iq2d + jj*n + r] = QG(r+1, six[ct1+ct2+ct3+jj+1]);
  }
  __syncthreads();
  for (int idx = tid; idx < ct4*n; idx += 256){
    int jj = idx / n, r = idx % n;
    QG(r+1, k+jj+1) = q2a[iq2d + jj*n + r];
  }
  for (int jj = k+1+tid; jj <= n; jj += 256) sd[jj] = sz[jj];
  __syncthreads();
  for (int j = 1+tid; j <= k; j += 256){
    int info; double dj;
    dlaed4(k, j, sdl, sw, Ta + (j-1), n, rho, dj, info);
    sd[j] = dj;
  }
  __syncthreads();
  if (k == 2){
    if (tid == 0){
      for (int j = 1; j <= 2; j++){
        double a1 = TS(1,j), a2 = TS(2,j);
        TS(1,j) = (sic[1] == 1) ? a1 : a2;
        TS(2,j) = (sic[2] == 1) ? a1 : a2;
      }
    }
    __syncthreads();
  } else if (k >= 3){
    for (int i = 1+tid; i <= k; i += 256) sst[i] = sw[i];
    __syncthreads();
    for (int i = 1+tid; i <= k; i += 256){
      double prod = TS(i,i);
      for (int j2 = 1; j2 < i; j2++) prod *= TS(i,j2)/(sdl[i] - sdl[j2]);
      for (int j2 = i+1; j2 <= k; j2++) prod *= TS(i,j2)/(sdl[i] - sdl[j2]);
      sw[i] = fsign(sqrt(-prod), sst[i]);
    }
    __syncthreads();
    for (int j2 = 1+tid; j2 <= k; j2 += 256){
      double nrm = 0.0;
      for (int i = 1; i <= k; i++){
        double v = sw[i]/TS(i,j2);
        sa[(size_t)(i-1)*n + (j2-1)] = v;
        nrm += v*v;
      }
      nrm = sqrt(nrm);
      for (int i = 1; i <= k; i++) TS(i,j2) = sa[(size_t)(sic[i]-1)*n + (j2-1)]/nrm;
    }
    __syncthreads();
  }
  {
    const int n12 = ct1 + ct2, n23 = ct2 + ct3;
    const size_t iq2 = (size_t)nn1*n12;
    const int kf = k & ~7;
    const int njb = kf >> 3;
    for (int idx = tid; idx < njb*nn2; idx += 256){
      int jb = idx / nn2, r = idx % nn2;
      int j2b = jb << 3;
      double a0=0,a1=0,a2=0,a3=0,a4=0,a5=0,a6=0,a7=0;
      const double* qp = q2a + iq2 + r;
      const double* tp = Ta + (size_t)ct1*n + j2b;
      for (int t2 = 0; t2 < n23; t2++){
        double q = qp[(size_t)t2*nn2];
        const double* tr = tp + (size_t)t2*n;
        a0 += q*tr[0]; a1 += q*tr[1]; a2 += q*tr[2]; a3 += q*tr[3];
        a4 += q*tr[4]; a5 += q*tr[5]; a6 += q*tr[6]; a7 += q*tr[7];
      }
      double* og = Q0 + (s0-1 + nn1 + r) + (size_t)(s0-1 + j2b)*LDQ;
      og[0] = a0; og[(size_t)1*LDQ] = a1; og[(size_t)2*LDQ] = a2; og[(size_t)3*LDQ] = a3;
      og[(size_t)4*LDQ] = a4; og[(size_t)5*LDQ] = a5; og[(size_t)6*LDQ] = a6; og[(size_t)7*LDQ] = a7;
    }
    for (int idx = tid; idx < (k-kf)*nn2; idx += 256){
      int j2 = kf + idx / nn2, r = idx % nn2;
      double acc = 0.0;
      for (int t2 = 0; t2 < n23; t2++)
        acc += q2a[iq2 + (size_t)t2*nn2 + r] * TS(ct1 + t2 + 1, j2 + 1);
      QG(nn1 + r + 1, j2 + 1) = acc;
    }
    for (int idx = tid; idx < njb*nn1; idx += 256){
      int jb = idx / nn1, r = idx % nn1;
      int j2b = jb << 3;
      double a0=0,a1=0,a2=0,a3=0,a4=0,a5=0,a6=0,a7=0;
      const double* qp = q2a + r;
      const double* tp = Ta + j2b;
      for (int t2 = 0; t2 < n12; t2++){
        double q = qp[(size_t)t2*nn1];
        const double* tr = tp + (size_t)t2*n;
        a0 += q*tr[0]; a1 += q*tr[1]; a2 += q*tr[2]; a3 += q*tr[3];
        a4 += q*tr[4]; a5 += q*tr[5]; a6 += q*tr[6]; a7 += q*tr[7];
      }
      double* og = Q0 + (s0-1 + r) + (size_t)(s0-1 + j2b)*LDQ;
      og[0] = a0; og[(size_t)1*LDQ] = a1; og[(size_t)2*LDQ] = a2; og[(size_t)3*LDQ] = a3;
      og[(size_t)4*LDQ] = a4; og[(size_t)5*LDQ] = a5; og[(size_t)6*LDQ] = a6; og[(size_t)7*LDQ] = a7;
    }
    for (int idx = tid; idx < (k-kf)*nn1; idx += 256){
      int j2 = kf + idx / nn1, r = idx % nn1;
      double acc = 0.0;
      for (int t2 = 0; t2 < n12; t2++)
        acc += q2a[(size_t)t2*nn1 + r] * TS(t2 + 1, j2 + 1);
      QG(r + 1, j2 + 1) = acc;
    }
    __syncthreads();
  }
  if (tid == 0) dlamrg(k, n - k, sd, 1, -1, siq);
  __syncthreads();
  for (int i = 1+tid; i <= n; i += 256){
    d1[s0-1+i] = sd[i];
    indxqg[s0-1+i] = siq[i];
  }
#undef QG
#undef TS
}

// ======================= eig stage 4a: permute columns + d =======================
__global__ __launch_bounds__(256) void eig_perm(
    double* __restrict__ Vg, double* __restrict__ sg,
    double* __restrict__ f64g, const int* __restrict__ i32g){
  const int mtx = blockIdx.x;
  const int tid = threadIdx.x;
  double* Q0 = Vg + (size_t)mtx*65536;
  double* sa = sg + (size_t)mtx*65536;
  double* F  = f64g + (size_t)mtx*4096;
  const int* IA = i32g + (size_t)mtx*4096;
  __shared__ double shd[256];

  for (int idx = tid; idx < 65536; idx += 256){
    int jc = idx >> 8;
    int r = idx & 255;
    int srcc = IA[jc];
    sa[idx] = Q0[r + (size_t)(srcc-1)*LDQ];
  }
  if (tid == 0){
    double orgnrm = F[3208];
    for (int i = 0; i < 256; i++) shd[i] = F[IA[i]-1]*orgnrm;
  }
  __syncthreads();
  F[tid] = shd[tid];
}

// ======================= eig stage 4b: back-transform (LDS columns, 4-acc dot) =================
__global__ __launch_bounds__(64) void eig_bt(
    const double* __restrict__ covg, const double* __restrict__ sg,
    double* __restrict__ Vg, const double* __restrict__ f64g){
  extern __shared__ double lds[];
  const int mtx = blockIdx.x >> 2;
  const int grp = blockIdx.x & 3;
  const int tid = threadIdx.x;
  const double* A0 = covg + (size_t)mtx*65536;
  const double* sa = sg + (size_t)mtx*65536 + (size_t)grp*64*LDQ;
  double* Qo = Vg + (size_t)mtx*65536 + (size_t)grp*64*LDQ;
  const double* tau1 = f64g + (size_t)mtx*4096 + 512 - 1;

  for (int j = 0; j < 64; j++){
    const double* src = sa + (size_t)j*LDQ;
    double* dstc = lds + (size_t)j*257;
    for (int r = tid; r < 256; r += 64) dstc[r] = src[r];
  }
  __syncthreads();
  double* col = lds + (size_t)tid*257;
  for (int i1 = NEIG-1; i1 >= 1; i1--){
    double ti = tau1[i1];
    if (ti == 0.0) continue;
    const double* av = A0 + (size_t)(i1-1)*LDQ;
    double s0 = 0.0, s1 = 0.0, s2 = 0.0, s3 = 0.0;
    int r = i1+1;
    for (; r + 3 < NEIG; r += 4){
      s0 += av[r]*col[r];
      s1 += av[r+1]*col[r+1];
      s2 += av[r+2]*col[r+2];
      s3 += av[r+3]*col[r+3];
    }
    for (; r < NEIG; r++) s0 += av[r]*col[r];
    double s = (col[i1] + ((s0+s1)+(s2+s3)))*ti;
    col[i1] -= s;
    for (int r2 = i1+1; r2 < NEIG; r2++) col[r2] -= s*av[r2];
  }
  __syncthreads();
  for (int j = 0; j < 64; j++){
    double* dst = Qo + (size_t)j*LDQ;
    const double* srcc = lds + (size_t)j*257;
    for (int r = tid; r < 256; r += 64) dst[r] = srcc[r];
  }
}

// ======================= pipeline kernels =======================
__global__ __launch_bounds__(256) void k1_qkv(const float* __restrict__ x, const float* __restrict__ wqkv,
                                              float* __restrict__ qkvb){
  int idx = blockIdx.x*256 + threadIdx.x;
  if (idx >= 2*48*65536) return;
  int pix = idx & 65535;
  int o = (idx >> 16) % 48;
  int b = idx / (48*65536);
  const float* xb = x + (size_t)b*16*65536 + pix;
  const float* wr = wqkv + o*16;
  float acc = 0.f;
#pragma unroll
  for (int c = 0; c < 16; c++) acc += wr[c]*xb[(size_t)c*65536];
  qkvb[idx] = acc;
}

__global__ __launch_bounds__(256) void k2_dw_patch(const float* __restrict__ qkvb, const float* __restrict__ wdw,
                                                   float* __restrict__ pq, float* __restrict__ pk, float* __restrict__ pv){
  int idx = blockIdx.x*256 + threadIdx.x;
  if (idx >= 2*48*65536) return;
  int j = idx & 255, i = (idx >> 8) & 255;
  int o = (idx >> 16) % 48, b = idx / (48*65536);
  const float* base = qkvb + ((size_t)(b*48 + o) << 16);
  const float* w9 = wdw + o*9;
  float acc = 0.f;
  for (int di = 0; di < 3; di++){
    int ii = i + di - 1;
    if (ii < 0 || ii > 255) continue;
    for (int dj = 0; dj < 3; dj++){
      int jj = j + dj - 1;
      if (jj < 0 || jj > 255) continue;
      acc += w9[di*3+dj]*base[(ii << 8) + jj];
    }
  }
  int part = o / 16, c16 = o % 16;
  int h = c16 >> 2, ch = c16 & 3;
  int m = ((b*4 + h) << 2) + ch;
  int p = ((i >> 4) << 4) + (j >> 4);
  int dd = ((i & 15) << 4) + (j & 15);
  float* dst = (part == 0) ? pq : (part == 1) ? pk : pv;
  dst[((size_t)m << 16) + (p << 8) + dd] = acc;
}

__global__ __launch_bounds__(256) void k3_norms(const float* __restrict__ pq, const float* __restrict__ pk,
                                                double* __restrict__ f64a){
  int m = blockIdx.x;
  int n = threadIdx.x;
  const float* qrow = pq + ((size_t)m << 16) + (n << 8);
  const float* krow = pk + ((size_t)m << 16) + (n << 8);
  double sq = 0.0, sk = 0.0;
  for (int dd = 0; dd < 256; dd++){
    double a = (double)qrow[dd]; sq += a*a;
    double bb = (double)krow[dd]; sk += bb*bb;
  }
  double* F = f64a + (size_t)m*4096;
  F[2688 + n] = fmax(sqrt(sq), 1e-12);
  F[2944 + n] = fmax(sqrt(sk), 1e-12);
}

__global__ __launch_bounds__(256) void k4_attn(const float* __restrict__ pq, const float* __restrict__ pk,
                                               const float* __restrict__ temp4, const double* __restrict__ f64a,
                                               double* __restrict__ xc){
  int m = blockIdx.x >> 8;
  int n = blockIdx.x & 255;
  int t = threadIdx.x;
  __shared__ float qrow[256];
  __shared__ double red[256];
  qrow[t] = pq[((size_t)m << 16) + (n << 8) + t];
  __syncthreads();
  const double* F = f64a + (size_t)m*4096;
  double qn = F[2688 + n], kn = F[2944 + t];
  const float* krow = pk + ((size_t)m << 16) + (t << 8);
  double s = 0.0;
  for (int dd = 0; dd < 256; dd++) s += (double)qrow[dd]*(double)krow[dd];
  int ch = m & 3;
  s = s/(qn*kn)*(double)temp4[ch];
  red[t] = s; __syncthreads();
  for (int st = 128; st > 0; st >>= 1){ if (t < st) red[t] = fmax(red[t], red[t+st]); __syncthreads(); }
  double mx = red[0]; __syncthreads();
  double ev = exp(s - mx);
  red[t] = ev; __syncthreads();
  for (int st = 128; st > 0; st >>= 1){ if (t < st) red[t] += red[t+st]; __syncthreads(); }
  double sum = red[0]; __syncthreads();
  double p = ev/sum;
  red[t] = p; __syncthreads();
  for (int st = 128; st > 0; st >>= 1){ if (t < st) red[t] += red[t+st]; __syncthreads(); }
  double mean = red[0]/256.0;
  xc[((size_t)m << 16) + (n << 8) + t] = p - mean;
}

__global__ __launch_bounds__(256) void k5_cov(const double* __restrict__ xc, double* __restrict__ cov){
  int m = blockIdx.x >> 8, i = blockIdx.x & 255, j = threadIdx.x;
  __shared__ double xi[256];
  const double* base = xc + ((size_t)m << 16);
  xi[j] = base[(i << 8) + j];
  __syncthreads();
  const double* xj = base + (j << 8);
  double acc = 0.0;
  for (int dd = 0; dd < 256; dd++) acc += xi[dd]*xj[dd];
  cov[((size_t)m << 16) + (size_t)j*256 + i] = acc/255.0;  // col-major (i,j)
}

__global__ __launch_bounds__(256) void k5b_trace(const double* __restrict__ cov, double* __restrict__ f64a){
  int m = blockIdx.x, t = threadIdx.x;
  __shared__ double red[256];
  red[t] = cov[((size_t)m << 16) + (size_t)t*257];
  __syncthreads();
  for (int st = 128; st > 0; st >>= 1){ if (t < st) red[t] += red[t+st]; __syncthreads(); }
  if (t == 0) f64a[(size_t)m*4096 + 3200] = red[0];
}

__global__ __launch_bounds__(256) void k5c_scale(double* __restrict__ cov, const double* __restrict__ f64a){
  size_t idx = (size_t)blockIdx.x*256 + threadIdx.x;
  int m = (int)(idx >> 16);
  int e = (int)(idx & 65535);
  double tra = f64a[(size_t)m*4096 + 3200];
  double v = cov[idx]/tra;
  if ((e & 255) == (e >> 8)) v += 1e-5;
  cov[idx] = v;
}

// ======================= tail kernels =======================
__global__ __launch_bounds__(256) void k7_y(const double* __restrict__ V, const float* __restrict__ wfr,
                                            double* __restrict__ Y, double* __restrict__ Yt){
  int m = blockIdx.x >> 8, n = blockIdx.x & 255, p = threadIdx.x;
  if (p >= 100) return;
  const double* Vm = V + ((size_t)m << 16);
  const float* wr = wfr + p*100;
  double acc = 0.0;
  for (int q = 0; q < 100; q++) acc += Vm[n + ((size_t)(255 - q) << 8)]*(double)wr[q];
  Y[(((size_t)m << 8) + n)*128 + p] = acc;
  Yt[(((size_t)m << 7) + p)*256 + n] = acc;
}

__global__ __launch_bounds__(256) void k8_a(const double* __restrict__ Y, const double* __restrict__ Yt,
                                            double* __restrict__ A){
  int m = blockIdx.x >> 8, n = blockIdx.x & 255, j = threadIdx.x;
  const double* yn = Y + (((size_t)m << 8) + n)*128;
  const double* ytb = Yt + ((size_t)m << 7)*256 + j;
  double acc = 0.0;
  for (int p = 0; p < 100; p++) acc += yn[p]*ytb[(size_t)p*256];
  A[((size_t)m << 16) + (n << 8) + j] = acc;
}

__global__ __launch_bounds__(256) void k9_av(const double* __restrict__ A, const float* __restrict__ pv,
                                             float* __restrict__ out1){
  int m = blockIdx.x >> 8, n = blockIdx.x & 255, dd = threadIdx.x;
  __shared__ double arow[256];
  arow[dd] = A[((size_t)m << 16) + (n << 8) + dd];
  __syncthreads();
  const float* vb = pv + ((size_t)m << 16);
  double acc = 0.0;
  for (int mm = 0; mm < 256; mm++) acc += arow[mm]*(double)vb[(mm << 8) + dd];
  out1[((size_t)m << 16) + (n << 8) + dd] = (float)acc;
}

__global__ __launch_bounds__(256) void k10_final(const float* __restrict__ out1, const float* __restrict__ wpo,
                                                 float* __restrict__ out){
  int idx = blockIdx.x*256 + threadIdx.x;
  if (idx >= 2*16*65536) return;
  int d2 = idx & 255, p2 = (idx >> 8) & 255;
  int o = (idx >> 16) & 15, b = idx >> 20;
  int n1 = ((p2 >> 4) << 4) + (d2 >> 4);
  int dold = ((p2 & 15) << 4) + (d2 & 15);
  const float* wr = wpo + o*16;
  float acc = 0.f;
  for (int c = 0; c < 16; c++){
    int h = c >> 2, ch = c & 3;
    int m = ((b*4 + h) << 2) + ch;
    acc += wr[c]*out1[((size_t)m << 16) + (n1 << 8) + dold];
  }
  out[idx] = acc;
}

// ======================= host launcher =======================
extern "C" void kernel_launch(void* const* d_in, const int* in_sizes, int n_in,
                              void* d_out, int out_size, void* d_ws, size_t ws_size,
                              hipStream_t stream){
  const float* x = (const float*)d_in[0];
  const float* w_qkv = (const float*)d_in[1];
  const float* w_dw = (const float*)d_in[2];
  const float* temperature = (const float*)d_in[3];
  const float* w_fr = (const float*)d_in[4];
  const float* w_po = (const float*)d_in[5];
  float* out = (float*)d_out;

  char* ws = (char*)d_ws;
  size_t off = 0;
  auto alloc = [&](size_t bytes) -> void* {
    void* p = ws + off;
    off += (bytes + 255) & ~(size_t)255;
    return p;
  };
  float* qkvb = (float*)alloc(sizeof(float)*2*48*65536);   // reused as eig T-scratch after k2
  float* pq   = (float*)alloc(sizeof(float)*32*65536);
  float* pk   = (float*)alloc(sizeof(float)*32*65536);     // reused as Yt after k4
  float* pv   = (float*)alloc(sizeof(float)*32*65536);
  double* xc  = (double*)alloc(sizeof(double)*32*65536);   // later reused as A
  double* cov = (double*)alloc(sizeof(double)*32*65536);
  double* V   = (double*)alloc(sizeof(double)*32*65536);
  double* q2  = (double*)alloc(sizeof(double)*32*65536);
  double* sbuf= (double*)alloc(sizeof(double)*32*65536);
  double* Y   = (double*)alloc(sizeof(double)*32*256*128);
  float* out1 = (float*)alloc(sizeof(float)*32*65536);
  double* f64a= (double*)alloc(sizeof(double)*32*4096);
  int* i32a   = (int*)alloc(sizeof(int)*32*4096);
  if (off > ws_size) return;

  double* Tg = (double*)qkvb;   // qkvb dead after k2; fully rewritten by k1 each call
  double* Yt = (double*)pk;     // pk dead after k4; 8,388,608B == 32*128*256*8 exactly

  // Recreate call-1's initial conditions every call: zero the eig scratch.
  hipMemsetAsync(q2,   0, sizeof(double)*32*65536, stream);
  hipMemsetAsync(sbuf, 0, sizeof(double)*32*65536, stream);
  hipMemsetAsync(f64a, 0, sizeof(double)*32*4096,  stream);
  hipMemsetAsync(i32a, 0, sizeof(int)*32*4096,     stream);

  hipFuncSetAttribute((const void*)eig_bt, hipFuncAttributeMaxDynamicSharedMemorySize, 64*257*8);

  dim3 blk(256);
  k1_qkv<<<(2*48*65536 + 255)/256, blk, 0, stream>>>(x, w_qkv, qkvb);
  k2_dw_patch<<<(2*48*65536 + 255)/256, blk, 0, stream>>>(qkvb, w_dw, pq, pk, pv);
  k3_norms<<<32, blk, 0, stream>>>(pq, pk, f64a);
  k4_attn<<<8192, blk, 0, stream>>>(pq, pk, temperature, f64a, xc);
  k5_cov<<<8192, blk, 0, stream>>>(xc, cov);
  k5b_trace<<<32, blk, 0, stream>>>(cov, f64a);
  k5c_scale<<<8192, blk, 0, stream>>>(cov, f64a);

  eig_tridiag<<<32, 1024, 0, stream>>>(cov, V, f64a);
  eig_leaves<<<512, 64, 0, stream>>>(V, f64a, i32a);
  eig_merge<<<32*8, blk, 0, stream>>>(V, q2, sbuf, Tg, f64a, i32a, 32, 8);
  eig_merge<<<32*4, blk, 0, stream>>>(V, q2, sbuf, Tg, f64a, i32a, 64, 4);
  eig_merge<<<32*2, blk, 0, stream>>>(V, q2, sbuf, Tg, f64a, i32a, 128, 2);
  eig_merge<<<32*1, blk, 0, stream>>>(V, q2, sbuf, Tg, f64a, i32a, 256, 1);
  eig_perm<<<32, blk, 0, stream>>>(V, sbuf, f64a, i32a);
  eig_bt<<<128, 64, 64*257*8, stream>>>(cov, sbuf, V, f64a);

  k7_y<<<8192, blk, 0, stream>>>(V, w_fr, Y, Yt);
  k8_a<<<8192, blk, 0, stream>>>(Y, Yt, xc);
  k9_av<<<8192, blk, 0, stream>>>(xc, pv, out1);
  k10_final<<<(2*16*65536 + 255)/256, blk, 0, stream>>>(out1, w_po, out);
  (void)in_sizes; (void)n_in; (void)out_size;
}